// Round 12
// baseline (2863.004 us; speedup 1.0000x reference)
//
#include <hip/hip_runtime.h>
#include <hip/hip_bf16.h>

// Grouped Residual VQ: G=2, Q=8, K=1024, CD=256, DIM=1280 (DG=640), T=32768.
//
// Round 12: big-phase streaming. Token fragments register-stationary (as r11).
// Codebook streamed in 64-code x 256-dim x hi/lo chunks (64 KB), double-
// buffered in LDS -> only 2 barriers per 64-code chunk (256 barriers/kernel
// vs 2048 in r11), prefetch depth ~7500 cyc of MFMA >> gather latency.
// Scoring, two-min w/ first-index ties, EPS=2e-3 + exact f64 rescan, STE
// rounding chain, deterministic loss: verbatim semantics from passing r11.

#define G 2
#define Q 8
#define KCODES 1024
#define CD 256
#define DIMV 1280
#define DG 640
#define T 32768
#define TM 256

#define WS_H      ((size_t)0)
#define WS_RES    (WS_H + (size_t)G*T*CD)
#define WS_CNORM  (WS_RES + (size_t)G*T*CD)
#define WS_CN64   (WS_CNORM + (size_t)G*Q*KCODES)
#define WS_LPARTD (WS_CN64 + (size_t)2*G*Q*KCODES)

#define OUT_IDX   ((size_t)T*DIMV)
#define OUT_LOSS  (OUT_IDX + (size_t)G*T*Q)

#define EPS_REFINE 2e-3f

typedef __attribute__((ext_vector_type(8))) short s16x8;
typedef __attribute__((ext_vector_type(4))) float f32x4;

static __device__ __forceinline__ unsigned short f2bf(float v) {
    __hip_bfloat16 b = __float2bfloat16(v);
    return *(unsigned short*)&b;
}
static __device__ __forceinline__ float bf2f(unsigned short u) {
    __hip_bfloat16 b = *(__hip_bfloat16*)&u;
    return __bfloat162float(b);
}

static __device__ __forceinline__ void gl_lds16(const void* g, void* l) {
    __builtin_amdgcn_global_load_lds(
        (const __attribute__((address_space(1))) unsigned int*)g,
        (__attribute__((address_space(3))) unsigned int*)l, 16, 0, 0);
}

__device__ __forceinline__ float np_half_sumsq(const float4* __restrict__ p) {
    float4 a = p[0], b = p[1];
    float r0=a.x*a.x, r1=a.y*a.y, r2=a.z*a.z, r3=a.w*a.w;
    float r4=b.x*b.x, r5=b.y*b.y, r6=b.z*b.z, r7=b.w*b.w;
#pragma unroll
    for (int i = 1; i < 16; i++) {
        a = p[2*i]; b = p[2*i+1];
        r0 += a.x*a.x; r1 += a.y*a.y; r2 += a.z*a.z; r3 += a.w*a.w;
        r4 += b.x*b.x; r5 += b.y*b.y; r6 += b.z*b.z; r7 += b.w*b.w;
    }
    return ((r0+r1)+(r2+r3)) + ((r4+r5)+(r6+r7));
}

// ---------------- K1: codebook norms (f32 + exact f64) ----------------
__global__ void k_norms(const float* __restrict__ cb, float* __restrict__ ws) {
    int r = blockIdx.x * 256 + threadIdx.x;
    const float4* row = (const float4*)(cb + (size_t)r * CD);
    ws[WS_CNORM + r] = np_half_sumsq(row) + np_half_sumsq(row + 32);
    double s0=0, s1=0, s2=0, s3=0;
#pragma unroll 8
    for (int e = 0; e < 64; e++) {
        float4 v = row[e];
        s0 = fma((double)v.x,(double)v.x,s0); s1 = fma((double)v.y,(double)v.y,s1);
        s2 = fma((double)v.z,(double)v.z,s2); s3 = fma((double)v.w,(double)v.w,s3);
    }
    ((double*)(ws + WS_CN64))[r] = (s0+s1)+(s2+s3);
}

// ---------------- K1b: codebook bf16 hi/lo split ----------------
__global__ void k_split(const float* __restrict__ cb, short* __restrict__ cbh,
                        short* __restrict__ cbl) {
    size_t i = ((size_t)blockIdx.x * 256 + threadIdx.x) * 4;
    float4 v = *(const float4*)(cb + i);
    unsigned short h0=f2bf(v.x), h1=f2bf(v.y), h2=f2bf(v.z), h3=f2bf(v.w);
    *(short4*)(cbh + i) = make_short4((short)h0,(short)h1,(short)h2,(short)h3);
    *(short4*)(cbl + i) = make_short4((short)f2bf(v.x - bf2f(h0)), (short)f2bf(v.y - bf2f(h1)),
                                      (short)f2bf(v.z - bf2f(h2)), (short)f2bf(v.w - bf2f(h3)));
}

// ---------------- K2: input projection h = x_g @ Win_g^T + bin ----------------
__global__ __launch_bounds__(256) void k_proj_in(const float* __restrict__ x,
                                                 const float* __restrict__ Win,
                                                 const float* __restrict__ bin,
                                                 float* __restrict__ ws) {
    __shared__ float As[32][65];
    __shared__ float Bs[32][65];
    const int g  = blockIdx.z;
    const int t0 = blockIdx.x * 64;
    const int c0 = blockIdx.y * 64;
    const int tid = threadIdx.x;
    const int tx = tid & 15, ty = tid >> 4;
    float acc[4][4] = {};
    const float* Ab = x + (size_t)t0 * DIMV + (size_t)g * DG;
    const float* Bb = Win + (size_t)g * CD * DG + (size_t)c0 * DG;

    for (int k0 = 0; k0 < DG; k0 += 32) {
        __syncthreads();
#pragma unroll
        for (int j = 0; j < 8; j++) {
            int lin = j * 256 + tid;
            int k = lin & 31, r = lin >> 5;
            As[k][r] = Ab[(size_t)r * DIMV + k0 + k];
            Bs[k][r] = Bb[(size_t)r * DG + k0 + k];
        }
        __syncthreads();
#pragma unroll
        for (int k = 0; k < 32; k++) {
            float a[4], b[4];
#pragma unroll
            for (int i = 0; i < 4; i++) a[i] = As[k][ty + 16 * i];
#pragma unroll
            for (int j = 0; j < 4; j++) b[j] = Bs[k][tx + 16 * j];
#pragma unroll
            for (int i = 0; i < 4; i++)
#pragma unroll
                for (int j = 0; j < 4; j++) acc[i][j] = fmaf(a[i], b[j], acc[i][j]);
        }
    }
#pragma unroll
    for (int i = 0; i < 4; i++) {
        int t = t0 + ty + 16 * i;
        float* hrow = ws + WS_H + ((size_t)g * T + t) * CD;
#pragma unroll
        for (int j = 0; j < 4; j++) {
            int c = c0 + tx + 16 * j;
            hrow[c] = acc[i][j] + bin[g * CD + c];
        }
    }
}

// ---------------- K3: fused ResidualVQ (big-phase codebook streaming) ----------------
// 512 threads = 8 waves; wave owns 32 tokens (2 col-sets of 16), fragments in
// registers. Codebook chunk: [pl 2][dc 8][ku 4][code 64] s16x8 = 64 KB, x2 buf.
__global__ __launch_bounds__(512, 2) void k_rvq(const float* __restrict__ cb,
                                                float* __restrict__ ws,
                                                float* __restrict__ out,
                                                const short* __restrict__ cbh,
                                                const short* __restrict__ cbl) {
    __shared__ s16x8 CbV[2][4096];     // 128 KB
    __shared__ float cnS[KCODES];
    __shared__ float mmv1[TM], mmv2[TM];
    __shared__ int   mmi[TM];
    __shared__ double lredD[8];

    const int g  = blockIdx.y;
    const int t0 = blockIdx.x * TM;
    const int tid = threadIdx.x;
    const int lane = tid & 63, l15 = lane & 15, l4 = lane >> 4;
    const int wv = tid >> 6;
    const int tx = tid & 15, ty = tid >> 4;        // ty 0..31
    const size_t gT = (size_t)g * T;
    float* hbuf = ws + WS_H;
    float* rbuf = ws + WS_RES;
    const float* cng = ws + WS_CNORM + (size_t)g * Q * KCODES;
    double* lpD = (double*)(ws + WS_LPARTD);

    // staging geometry: 8 gl_lds/thread per chunk; unit u -> (pl, dc, ku, code)
    int cpl[8], coff[8];
#pragma unroll
    for (int k = 0; k < 8; k++) {
        int u = (wv * 8 + k) * 64 + lane;          // 0..4095
        cpl[k] = u >> 11;
        int rem = u & 2047;
        int dcx = rem >> 8, ku = (rem >> 6) & 3, code = rem & 63;
        coff[k] = code * CD + dcx * 32 + ku * 8;
    }

    for (int q = 0; q < Q; q++) {
        const float* cnq = cng + (size_t)q * KCODES;
        const double* cn64q = (const double*)(ws + WS_CN64) + ((size_t)g * Q + q) * KCODES;
        const float* cqb = cb + ((size_t)g * Q + q) * KCODES * CD;
        const short* cbhq = cbh + ((size_t)g * Q + q) * KCODES * CD;
        const short* cblq = cbl + ((size_t)g * Q + q) * KCODES * CD;
        const float* rsrc = (q == 0) ? hbuf : rbuf;

        cnS[tid] = cnq[tid];
        cnS[512 + tid] = cnq[512 + tid];

        // ---- token fragments: load f32 residual, split to bf16 hi/lo in regs ----
        s16x8 bfh[2][8], bfl[2][8];
#pragma unroll
        for (int s = 0; s < 2; s++) {
            const float* base = rsrc + (gT + t0 + wv * 32 + s * 16 + l15) * CD + l4 * 8;
#pragma unroll
            for (int dc = 0; dc < 8; dc++) {
                float4 u0 = *(const float4*)(base + dc * 32);
                float4 u1 = *(const float4*)(base + dc * 32 + 4);
                float v[8] = {u0.x,u0.y,u0.z,u0.w,u1.x,u1.y,u1.z,u1.w};
                s16x8 fh, fl;
#pragma unroll
                for (int e = 0; e < 8; e++) {
                    unsigned short hb = f2bf(v[e]);
                    fh[e] = (short)hb;
                    fl[e] = (short)f2bf(v[e] - bf2f(hb));
                }
                bfh[s][dc] = fh; bfl[s][dc] = fl;
            }
        }
        // stage chunk cc=0 into buf 0
#pragma unroll
        for (int k = 0; k < 8; k++)
            gl_lds16((cpl[k] ? cblq : cbhq) + coff[k], &CbV[0][(wv * 8 + k) * 64]);
        __syncthreads();                           // drains vmcnt: frags + chunk0 ready

        float tv1[2], tv2[2]; int tix[2];
#pragma unroll
        for (int s = 0; s < 2; s++) { tv1[s] = 3.4e38f; tv2[s] = 3.4e38f; tix[s] = 0x7fffffff; }

        for (int cc = 0; cc < 16; cc++) {
            f32x4 acc[2][4];
#pragma unroll
            for (int s = 0; s < 2; s++)
#pragma unroll
                for (int t = 0; t < 4; t++) acc[s][t] = (f32x4){0.f, 0.f, 0.f, 0.f};

            __builtin_amdgcn_s_barrier();          // all waves done reading buf[(cc+1)&1]
            if (cc + 1 < 16) {
                const size_t add = (size_t)(cc + 1) * 64 * CD;
#pragma unroll
                for (int k = 0; k < 8; k++)
                    gl_lds16((cpl[k] ? cblq : cbhq) + coff[k] + add,
                             &CbV[(cc + 1) & 1][(wv * 8 + k) * 64]);
                asm volatile("s_waitcnt vmcnt(8)" ::: "memory");   // chunk cc landed
            } else {
                asm volatile("s_waitcnt vmcnt(0)" ::: "memory");
            }
            __builtin_amdgcn_s_barrier();
            __builtin_amdgcn_sched_barrier(0);

            const int buf = cc & 1;
#pragma unroll
            for (int dc = 0; dc < 8; dc++) {
#pragma unroll
                for (int t = 0; t < 4; t++) {
                    int idx = dc * 256 + l4 * 64 + t * 16 + l15;
                    s16x8 ch = CbV[buf][idx];          // codebook hi
                    s16x8 cl = CbV[buf][2048 + idx];   // codebook lo
#pragma unroll
                    for (int s = 0; s < 2; s++) {
                        acc[s][t] = __builtin_amdgcn_mfma_f32_16x16x32_bf16(ch, bfh[s][dc], acc[s][t], 0, 0, 0);
                        acc[s][t] = __builtin_amdgcn_mfma_f32_16x16x32_bf16(ch, bfl[s][dc], acc[s][t], 0, 0, 0);
                        acc[s][t] = __builtin_amdgcn_mfma_f32_16x16x32_bf16(cl, bfh[s][dc], acc[s][t], 0, 0, 0);
                    }
                }
            }
            // ---- score chunk cc: vv = ||c||^2 - 2 r.c ; per-lane scalar two-min ----
#pragma unroll
            for (int s = 0; s < 2; s++)
#pragma unroll
                for (int t = 0; t < 4; t++)
#pragma unroll
                    for (int r = 0; r < 4; r++) {
                        int c = cc * 64 + t * 16 + l4 * 4 + r;
                        float vv = fmaf(-2.f, acc[s][t][r], cnS[c]);
                        if (vv < tv1[s])       { tv2[s] = tv1[s]; tv1[s] = vv; tix[s] = c; }
                        else if (vv == tv1[s]) { tv2[s] = tv1[s]; if (c < tix[s]) tix[s] = c; }
                        else if (vv < tv2[s])  { tv2[s] = vv; }
                    }
        }

        // ---- merge the 4 same-token lanes (strides 16, 32) ----
#pragma unroll
        for (int s = 0; s < 2; s++) {
            float v1 = tv1[s], v2 = tv2[s]; int i1 = tix[s];
#pragma unroll
            for (int m = 16; m < 64; m <<= 1) {
                float w1 = __shfl_xor(v1, m, 64);
                float w2 = __shfl_xor(v2, m, 64);
                int   j1 = __shfl_xor(i1, m, 64);
                if (w1 < v1)       { v2 = fminf(v1, w2); v1 = w1; i1 = j1; }
                else if (w1 == v1) { v2 = v1; if (j1 < i1) i1 = j1; }
                else               { v2 = fminf(v2, w1); }
            }
            if (lane < 16) {
                int tok = wv * 32 + s * 16 + lane;
                mmv1[tok] = v1; mmv2[tok] = v2; mmi[tok] = i1;
            }
        }
        __syncthreads();

        // ---- exact f64 refinement for near-tie tokens (rare) ----
        int besti[8];
#pragma unroll 1
        for (int i = 0; i < 8; i++) {
            int tok = ty + 32 * i;
            besti[i] = mmi[tok];
            if (!(mmv2[tok] - mmv1[tok] < EPS_REFINE)) continue;
            const float4* rp4 = (const float4*)(rsrc + (gT + t0 + tok) * CD);
            double bv = 1e300; int bi = 0x7fffffff;
            for (int c = tx; c < KCODES; c += 16) {
                const float4* cp4 = (const float4*)(cqb + (size_t)c * CD);
                double a0=0, a1=0, a2=0, a3=0;
#pragma unroll 4
                for (int e = 0; e < 64; e++) {
                    float4 cv = cp4[e], rv = rp4[e];
                    a0 = fma((double)rv.x,(double)cv.x,a0); a1 = fma((double)rv.y,(double)cv.y,a1);
                    a2 = fma((double)rv.z,(double)cv.z,a2); a3 = fma((double)rv.w,(double)cv.w,a3);
                }
                double dd = fma(-2.0, (a0+a1)+(a2+a3), cn64q[c]);
                if (dd < bv) { bv = dd; bi = c; }
            }
#pragma unroll
            for (int m = 1; m < 16; m <<= 1) {
                double ov = __shfl_xor(bv, m, 64);
                int    oi = __shfl_xor(bi, m, 64);
                if (ov < bv || (ov == bv && oi < bi)) { bv = ov; bi = oi; }
            }
            besti[i] = bi;
        }

        // ---- idx out ----
        if (tx == 0) {
#pragma unroll
            for (int i = 0; i < 8; i++)
                out[OUT_IDX + (gT + t0 + ty + 32 * i) * Q + q] = (float)besti[i];
        }

        // ---- STE epilogue: res rounding-replicated ----
        double lacc = 0.0;
#pragma unroll
        for (int i = 0; i < 8; i++) {
            int t = ty + 32 * i;
            size_t off = (gT + t0 + t) * CD;
            const float4* cp = (const float4*)(cqb + (size_t)besti[i] * CD) + tx * 4;
            const float4* rp = (const float4*)(rsrc + off) + tx * 4;
            float4* wp = (float4*)(rbuf + off) + tx * 4;
#pragma unroll
            for (int e = 0; e < 4; e++) {
                float4 c4 = cp[e], r4 = rp[e];
                float4 res4;
                float tt, qq, rr;
                tt = __fsub_rn(c4.x, r4.x); qq = __fadd_rn(r4.x, tt); rr = __fsub_rn(r4.x, qq);
                lacc += (double)rr * rr; res4.x = rr;
                tt = __fsub_rn(c4.y, r4.y); qq = __fadd_rn(r4.y, tt); rr = __fsub_rn(r4.y, qq);
                lacc += (double)rr * rr; res4.y = rr;
                tt = __fsub_rn(c4.z, r4.z); qq = __fadd_rn(r4.z, tt); rr = __fsub_rn(r4.z, qq);
                lacc += (double)rr * rr; res4.z = rr;
                tt = __fsub_rn(c4.w, r4.w); qq = __fadd_rn(r4.w, tt); rr = __fsub_rn(r4.w, qq);
                lacc += (double)rr * rr; res4.w = rr;
                wp[e] = res4;
            }
        }
        // deterministic loss partial (f64)
#pragma unroll
        for (int m = 1; m < 64; m <<= 1) lacc += __shfl_xor(lacc, m, 64);
        __syncthreads();
        if ((tid & 63) == 0) lredD[tid >> 6] = lacc;
        __syncthreads();
        if (tid == 0)
            lpD[((size_t)g * Q + q) * 256 + blockIdx.x] =
                (((lredD[0] + lredD[1]) + (lredD[2] + lredD[3])) +
                 ((lredD[4] + lredD[5]) + (lredD[6] + lredD[7])));
        __syncthreads();   // drains rbuf stores before next q's fragment loads
    }
}

// ---------------- K4: output projection out = (h - res) @ Wout_g^T + bout ----------------
__global__ __launch_bounds__(256) void k_proj_out(const float* __restrict__ ws,
                                                  const float* __restrict__ Wout,
                                                  const float* __restrict__ bout,
                                                  float* __restrict__ out) {
    __shared__ float As[32][65];
    __shared__ float Bs[32][65];
    const int g  = blockIdx.z;
    const int t0 = blockIdx.x * 64;
    const int d0 = blockIdx.y * 64;
    const int tid = threadIdx.x;
    const int tx = tid & 15, ty = tid >> 4;
    float acc[4][4] = {};
    const float* Ah = ws + WS_H + ((size_t)g * T + t0) * CD;
    const float* Ar = ws + WS_RES + ((size_t)g * T + t0) * CD;
    const float* Bb = Wout + (size_t)g * DG * CD + (size_t)d0 * CD;

    for (int k0 = 0; k0 < CD; k0 += 32) {
        __syncthreads();
#pragma unroll
        for (int j = 0; j < 8; j++) {
            int lin = j * 256 + tid;
            int k = lin & 31, r = lin >> 5;
            size_t o = (size_t)r * CD + k0 + k;
            As[k][r] = Ah[o] - Ar[o];            // qout = h - res_final
            Bs[k][r] = Bb[o];
        }
        __syncthreads();
#pragma unroll
        for (int k = 0; k < 32; k++) {
            float a[4], b[4];
#pragma unroll
            for (int i = 0; i < 4; i++) a[i] = As[k][ty + 16 * i];
#pragma unroll
            for (int j = 0; j < 4; j++) b[j] = Bs[k][tx + 16 * j];
#pragma unroll
            for (int i = 0; i < 4; i++)
#pragma unroll
                for (int j = 0; j < 4; j++) acc[i][j] = fmaf(a[i], b[j], acc[i][j]);
        }
    }
#pragma unroll
    for (int i = 0; i < 4; i++) {
        int t = t0 + ty + 16 * i;
#pragma unroll
        for (int j = 0; j < 4; j++) {
            int d = d0 + tx + 16 * j;
            out[(size_t)t * DIMV + (size_t)g * DG + d] = acc[i][j] + bout[g * DG + d];
        }
    }
}

// ---------------- K5: deterministic loss reduction (f64 -> f32) ----------------
__global__ void k_loss(const float* __restrict__ ws, float* __restrict__ out) {
    int gq = blockIdx.x;
    const double* lpD = (const double*)(ws + WS_LPARTD);
    // only T/TM = 128 blocks per (g,q) wrote partials; rest of the 256 slots
    // are uninitialized workspace -> read as zero.
    double v = (threadIdx.x < (T / TM)) ? lpD[(size_t)gq * 256 + threadIdx.x] : 0.0;
#pragma unroll
    for (int m = 1; m < 64; m <<= 1) v += __shfl_xor(v, m, 64);
    __shared__ double red[4];
    if ((threadIdx.x & 63) == 0) red[threadIdx.x >> 6] = v;
    __syncthreads();
    if (threadIdx.x == 0)
        out[OUT_LOSS + gq] =
            (float)(((red[0] + red[1]) + (red[2] + red[3])) * (1.0 / 8388608.0));
}

extern "C" void kernel_launch(void* const* d_in, const int* in_sizes, int n_in,
                              void* d_out, int out_size, void* d_ws, size_t ws_size,
                              hipStream_t stream) {
    const float* x    = (const float*)d_in[0];
    const float* Win  = (const float*)d_in[1];
    const float* bin  = (const float*)d_in[2];
    const float* Wout = (const float*)d_in[3];
    const float* bout = (const float*)d_in[4];
    const float* cb   = (const float*)d_in[5];
    float* out = (float*)d_out;
    float* ws  = (float*)d_ws;

    // bf16 hi/lo codebook scratch in the not-yet-written quantized region of
    // d_out: 2*G*Q*K*CD bf16 = 4.2M f32-equiv << 41.9M f32 region.
    short* scr = (short*)d_out;
    short* cbh = scr;
    short* cbl = scr + (size_t)G * Q * KCODES * CD;

    hipLaunchKernelGGL(k_norms,    dim3(64),          dim3(256), 0, stream, cb, ws);
    hipLaunchKernelGGL(k_split,    dim3(4096),        dim3(256), 0, stream, cb, cbh, cbl);
    hipLaunchKernelGGL(k_proj_in,  dim3(T/64, 4, G),  dim3(256), 0, stream, x, Win, bin, ws);
    hipLaunchKernelGGL(k_rvq,      dim3(T/TM, G),     dim3(512), 0, stream, cb, ws, out, cbh, cbl);
    hipLaunchKernelGGL(k_proj_out, dim3(T/64, 10, G), dim3(256), 0, stream, ws, Wout, bout, out);
    hipLaunchKernelGGL(k_loss,     dim3(16),          dim3(256), 0, stream, ws, out);
}

// Round 13
// 2479.897 us; speedup vs baseline: 1.1545x; 1.1545x over previous
//
#include <hip/hip_runtime.h>
#include <hip/hip_bf16.h>

// Grouped Residual VQ: G=2, Q=8, K=1024, CD=256, DIM=1280 (DG=640), T=32768.
//
// Round 13: REGISTER-RESIDENT RESIDUAL across all 8 q-steps.
// 512 thr = 8 waves; wave owns 16 tokens (lane: l15 = token col, l4 = dim
// slice; 64 f32 dims + bf16 hi/lo frags per lane). Per q: split frags (VALU),
// stream codebook chunks (64 codes x 256 dims x hi/lo = 64 KB, dbuf, counted
// vmcnt(8)), score, merge 4 lanes/token, ballot-gated exact f64 rescan via
// LDS scratch, STE update in regs from gathered code rows. h read once (q=0),
// res written once (q=7). No per-q residual global traffic.

#define G 2
#define Q 8
#define KCODES 1024
#define CD 256
#define DIMV 1280
#define DG 640
#define T 32768
#define TM 128

#define WS_H      ((size_t)0)
#define WS_RES    (WS_H + (size_t)G*T*CD)
#define WS_CNORM  (WS_RES + (size_t)G*T*CD)
#define WS_CN64   (WS_CNORM + (size_t)G*Q*KCODES)
#define WS_LPARTD (WS_CN64 + (size_t)2*G*Q*KCODES)

#define OUT_IDX   ((size_t)T*DIMV)
#define OUT_LOSS  (OUT_IDX + (size_t)G*T*Q)

#define EPS_REFINE 2e-3f

typedef __attribute__((ext_vector_type(8))) short s16x8;
typedef __attribute__((ext_vector_type(4))) float f32x4;

static __device__ __forceinline__ unsigned short f2bf(float v) {
    __hip_bfloat16 b = __float2bfloat16(v);
    return *(unsigned short*)&b;
}
static __device__ __forceinline__ float bf2f(unsigned short u) {
    __hip_bfloat16 b = *(__hip_bfloat16*)&u;
    return __bfloat162float(b);
}

static __device__ __forceinline__ void gl_lds16(const void* g, void* l) {
    __builtin_amdgcn_global_load_lds(
        (const __attribute__((address_space(1))) unsigned int*)g,
        (__attribute__((address_space(3))) unsigned int*)l, 16, 0, 0);
}

__device__ __forceinline__ float np_half_sumsq(const float4* __restrict__ p) {
    float4 a = p[0], b = p[1];
    float r0=a.x*a.x, r1=a.y*a.y, r2=a.z*a.z, r3=a.w*a.w;
    float r4=b.x*b.x, r5=b.y*b.y, r6=b.z*b.z, r7=b.w*b.w;
#pragma unroll
    for (int i = 1; i < 16; i++) {
        a = p[2*i]; b = p[2*i+1];
        r0 += a.x*a.x; r1 += a.y*a.y; r2 += a.z*a.z; r3 += a.w*a.w;
        r4 += b.x*b.x; r5 += b.y*b.y; r6 += b.z*b.z; r7 += b.w*b.w;
    }
    return ((r0+r1)+(r2+r3)) + ((r4+r5)+(r6+r7));
}

// ---------------- K1: codebook norms (f32 + exact f64) ----------------
__global__ void k_norms(const float* __restrict__ cb, float* __restrict__ ws) {
    int r = blockIdx.x * 256 + threadIdx.x;
    const float4* row = (const float4*)(cb + (size_t)r * CD);
    ws[WS_CNORM + r] = np_half_sumsq(row) + np_half_sumsq(row + 32);
    double s0=0, s1=0, s2=0, s3=0;
#pragma unroll 8
    for (int e = 0; e < 64; e++) {
        float4 v = row[e];
        s0 = fma((double)v.x,(double)v.x,s0); s1 = fma((double)v.y,(double)v.y,s1);
        s2 = fma((double)v.z,(double)v.z,s2); s3 = fma((double)v.w,(double)v.w,s3);
    }
    ((double*)(ws + WS_CN64))[r] = (s0+s1)+(s2+s3);
}

// ---------------- K1b: codebook bf16 hi/lo split ----------------
__global__ void k_split(const float* __restrict__ cb, short* __restrict__ cbh,
                        short* __restrict__ cbl) {
    size_t i = ((size_t)blockIdx.x * 256 + threadIdx.x) * 4;
    float4 v = *(const float4*)(cb + i);
    unsigned short h0=f2bf(v.x), h1=f2bf(v.y), h2=f2bf(v.z), h3=f2bf(v.w);
    *(short4*)(cbh + i) = make_short4((short)h0,(short)h1,(short)h2,(short)h3);
    *(short4*)(cbl + i) = make_short4((short)f2bf(v.x - bf2f(h0)), (short)f2bf(v.y - bf2f(h1)),
                                      (short)f2bf(v.z - bf2f(h2)), (short)f2bf(v.w - bf2f(h3)));
}

// ---------------- K2: input projection h = x_g @ Win_g^T + bin ----------------
__global__ __launch_bounds__(256) void k_proj_in(const float* __restrict__ x,
                                                 const float* __restrict__ Win,
                                                 const float* __restrict__ bin,
                                                 float* __restrict__ ws) {
    __shared__ float As[32][65];
    __shared__ float Bs[32][65];
    const int g  = blockIdx.z;
    const int t0 = blockIdx.x * 64;
    const int c0 = blockIdx.y * 64;
    const int tid = threadIdx.x;
    const int tx = tid & 15, ty = tid >> 4;
    float acc[4][4] = {};
    const float* Ab = x + (size_t)t0 * DIMV + (size_t)g * DG;
    const float* Bb = Win + (size_t)g * CD * DG + (size_t)c0 * DG;

    for (int k0 = 0; k0 < DG; k0 += 32) {
        __syncthreads();
#pragma unroll
        for (int j = 0; j < 8; j++) {
            int lin = j * 256 + tid;
            int k = lin & 31, r = lin >> 5;
            As[k][r] = Ab[(size_t)r * DIMV + k0 + k];
            Bs[k][r] = Bb[(size_t)r * DG + k0 + k];
        }
        __syncthreads();
#pragma unroll
        for (int k = 0; k < 32; k++) {
            float a[4], b[4];
#pragma unroll
            for (int i = 0; i < 4; i++) a[i] = As[k][ty + 16 * i];
#pragma unroll
            for (int j = 0; j < 4; j++) b[j] = Bs[k][tx + 16 * j];
#pragma unroll
            for (int i = 0; i < 4; i++)
#pragma unroll
                for (int j = 0; j < 4; j++) acc[i][j] = fmaf(a[i], b[j], acc[i][j]);
        }
    }
#pragma unroll
    for (int i = 0; i < 4; i++) {
        int t = t0 + ty + 16 * i;
        float* hrow = ws + WS_H + ((size_t)g * T + t) * CD;
#pragma unroll
        for (int j = 0; j < 4; j++) {
            int c = c0 + tx + 16 * j;
            hrow[c] = acc[i][j] + bin[g * CD + c];
        }
    }
}

// ---------------- K3: fused ResidualVQ (register-resident residual) ----------------
#define STE1(rv, cv) { float tt_ = __fsub_rn((cv), (rv)); float qq_ = __fadd_rn((rv), tt_); \
                       float rr_ = __fsub_rn((rv), qq_); lacc += (double)rr_ * rr_; (rv) = rr_; }

__global__ __launch_bounds__(512, 2) void k_rvq(const float* __restrict__ cb,
                                                float* __restrict__ ws,
                                                float* __restrict__ out,
                                                const short* __restrict__ cbh,
                                                const short* __restrict__ cbl) {
    __shared__ s16x8 CbV[2][4096];               // 128 KB codebook window
    __shared__ float cnS[KCODES];                // 4 KB
    __shared__ __align__(16) float refS[8][256]; // 8 KB per-wave refinement scratch
    __shared__ double lredD[8];

    const int g  = blockIdx.y;
    const int t0 = blockIdx.x * TM;
    const int tid = threadIdx.x;
    const int lane = tid & 63, l15 = lane & 15, l4 = lane >> 4;
    const int wv = tid >> 6;
    const size_t gT = (size_t)g * T;
    const int myTok = wv * 16 + l15;             // block-local token this lane co-owns
    const float* cng = ws + WS_CNORM + (size_t)g * Q * KCODES;
    double* lpD = (double*)(ws + WS_LPARTD);

    // codebook staging geometry (verbatim r12): 8 gl_lds/thread/chunk
    int cpl[8], coff[8];
#pragma unroll
    for (int k = 0; k < 8; k++) {
        int u = (wv * 8 + k) * 64 + lane;        // 0..4095
        cpl[k] = u >> 11;
        int rem = u & 2047;
        int dcx = rem >> 8, ku = (rem >> 6) & 3, code = rem & 63;
        coff[k] = code * CD + dcx * 32 + ku * 8;
    }

    // ---- residual (f32) lives in registers for the whole kernel ----
    float4 rA[8], rB[8];
    {
        const float* hrow = ws + WS_H + (gT + t0 + myTok) * CD + l4 * 8;
#pragma unroll
        for (int dc = 0; dc < 8; dc++) {
            rA[dc] = *(const float4*)(hrow + dc * 32);
            rB[dc] = *(const float4*)(hrow + dc * 32 + 4);
        }
    }

    for (int q = 0; q < Q; q++) {
        const float* cnq = cng + (size_t)q * KCODES;
        const double* cn64q = (const double*)(ws + WS_CN64) + ((size_t)g * Q + q) * KCODES;
        const float* cqb = cb + ((size_t)g * Q + q) * KCODES * CD;
        const short* cbhq = cbh + ((size_t)g * Q + q) * KCODES * CD;
        const short* cblq = cbl + ((size_t)g * Q + q) * KCODES * CD;

        cnS[tid] = cnq[tid];
        cnS[512 + tid] = cnq[512 + tid];

        // ---- split register residual to bf16 hi/lo fragments (pure VALU) ----
        s16x8 fh[8], fl[8];
#pragma unroll
        for (int dc = 0; dc < 8; dc++) {
            float v[8] = {rA[dc].x, rA[dc].y, rA[dc].z, rA[dc].w,
                          rB[dc].x, rB[dc].y, rB[dc].z, rB[dc].w};
            s16x8 th, tl;
#pragma unroll
            for (int e = 0; e < 8; e++) {
                unsigned short hb = f2bf(v[e]);
                th[e] = (short)hb;
                tl[e] = (short)f2bf(v[e] - bf2f(hb));
            }
            fh[dc] = th; fl[dc] = tl;
        }

        // stage chunk 0 into buf 0
#pragma unroll
        for (int k = 0; k < 8; k++)
            gl_lds16((cpl[k] ? cblq : cbhq) + coff[k], &CbV[0][(wv * 8 + k) * 64]);
        __syncthreads();                          // drains vmcnt: chunk0 + cnS ready

        float tv1 = 3.4e38f, tv2 = 3.4e38f;
        int   tix = 0x7fffffff;
        f32x4 acc[4];
#pragma unroll
        for (int t = 0; t < 4; t++) acc[t] = (f32x4){0.f, 0.f, 0.f, 0.f};

        for (int cc = 0; cc < 16; cc++) {
            __builtin_amdgcn_s_barrier();         // all waves done reading buf[(cc+1)&1]
            if (cc + 1 < 16) {
                const size_t add = (size_t)(cc + 1) * 64 * CD;
#pragma unroll
                for (int k = 0; k < 8; k++)
                    gl_lds16((cpl[k] ? cblq : cbhq) + coff[k] + add,
                             &CbV[(cc + 1) & 1][(wv * 8 + k) * 64]);
                asm volatile("s_waitcnt vmcnt(8)" ::: "memory");   // chunk cc landed
            } else {
                asm volatile("s_waitcnt vmcnt(0)" ::: "memory");
            }
            __builtin_amdgcn_s_barrier();
            __builtin_amdgcn_sched_barrier(0);

            const int buf = cc & 1;
#pragma unroll
            for (int dc = 0; dc < 8; dc++) {
#pragma unroll
                for (int t = 0; t < 4; t++) {
                    int idx = dc * 256 + l4 * 64 + t * 16 + l15;
                    s16x8 ch = CbV[buf][idx];
                    s16x8 cl2 = CbV[buf][2048 + idx];
                    acc[t] = __builtin_amdgcn_mfma_f32_16x16x32_bf16(ch, fh[dc], acc[t], 0, 0, 0);
                    acc[t] = __builtin_amdgcn_mfma_f32_16x16x32_bf16(ch, fl[dc], acc[t], 0, 0, 0);
                    acc[t] = __builtin_amdgcn_mfma_f32_16x16x32_bf16(cl2, fh[dc], acc[t], 0, 0, 0);
                }
            }
            // score chunk cc: vv = ||c||^2 - 2 r.c ; per-lane two-min (c ascending)
#pragma unroll
            for (int t = 0; t < 4; t++)
#pragma unroll
                for (int r = 0; r < 4; r++) {
                    int c = cc * 64 + t * 16 + l4 * 4 + r;
                    float vv = fmaf(-2.f, acc[t][r], cnS[c]);
                    if (vv < tv1)       { tv2 = tv1; tv1 = vv; tix = c; }
                    else if (vv == tv1) { tv2 = tv1; if (c < tix) tix = c; }
                    else if (vv < tv2)  { tv2 = vv; }
                }
#pragma unroll
            for (int t = 0; t < 4; t++) acc[t] = (f32x4){0.f, 0.f, 0.f, 0.f};
        }

        // ---- merge the 4 same-token lanes (strides 16, 32) ----
        {
            float v1 = tv1, v2 = tv2; int i1 = tix;
#pragma unroll
            for (int m = 16; m < 64; m <<= 1) {
                float w1 = __shfl_xor(v1, m, 64);
                float w2 = __shfl_xor(v2, m, 64);
                int   j1 = __shfl_xor(i1, m, 64);
                if (w1 < v1)       { v2 = fminf(v1, w2); v1 = w1; i1 = j1; }
                else if (w1 == v1) { v2 = v1; if (j1 < i1) i1 = j1; }
                else               { v2 = fminf(v2, w1); }
            }
            tv1 = v1; tv2 = v2; tix = i1;         // all 4 owner lanes hold final values
        }

        // ---- ballot-gated exact f64 refinement (rare) ----
        int besti = tix;
        unsigned long long flg = __ballot(tv2 - tv1 < EPS_REFINE) & 0xFFFFull;
        while (flg) {
            int l = __builtin_ctzll(flg); flg &= flg - 1;
            if (l15 == l) {                       // owner lanes dump f32 residual
#pragma unroll
                for (int dc = 0; dc < 8; dc++) {
                    *(float4*)(&refS[wv][dc * 32 + l4 * 8])     = rA[dc];
                    *(float4*)(&refS[wv][dc * 32 + l4 * 8 + 4]) = rB[dc];
                }
            }
            asm volatile("s_waitcnt lgkmcnt(0)" ::: "memory");
            __builtin_amdgcn_sched_barrier(0);
            const float4* rf4 = (const float4*)(&refS[wv][0]);
            double bv = 1e300; int bi = 0x7fffffff;
            for (int c = lane; c < KCODES; c += 64) {
                const float4* cp4 = (const float4*)(cqb + (size_t)c * CD);
                double a0=0, a1=0, a2=0, a3=0;
#pragma unroll 4
                for (int e = 0; e < 64; e++) {
                    float4 cv = cp4[e], rv = rf4[e];
                    a0 = fma((double)rv.x,(double)cv.x,a0); a1 = fma((double)rv.y,(double)cv.y,a1);
                    a2 = fma((double)rv.z,(double)cv.z,a2); a3 = fma((double)rv.w,(double)cv.w,a3);
                }
                double dd = fma(-2.0, (a0+a1)+(a2+a3), cn64q[c]);
                if (dd < bv) { bv = dd; bi = c; }
            }
#pragma unroll
            for (int m = 1; m < 64; m <<= 1) {
                double ov = __shfl_xor(bv, m, 64);
                int    oi = __shfl_xor(bi, m, 64);
                if (ov < bv || (ov == bv && oi < bi)) { bv = ov; bi = oi; }
            }
            if (l15 == l) besti = bi;
            asm volatile("s_waitcnt lgkmcnt(0)" ::: "memory");  // reads done before next dump
        }

        // ---- idx out (lane<16 holds token wv*16+lane) ----
        if (lane < 16)
            out[OUT_IDX + (gT + t0 + wv * 16 + lane) * Q + q] = (float)besti;

        // ---- STE update in registers from gathered code row ----
        double lacc = 0.0;
        {
            const float* crow = cqb + (size_t)besti * CD + l4 * 8;
#pragma unroll
            for (int dc = 0; dc < 8; dc++) {
                float4 c0 = *(const float4*)(crow + dc * 32);
                float4 c1 = *(const float4*)(crow + dc * 32 + 4);
                STE1(rA[dc].x, c0.x); STE1(rA[dc].y, c0.y);
                STE1(rA[dc].z, c0.z); STE1(rA[dc].w, c0.w);
                STE1(rB[dc].x, c1.x); STE1(rB[dc].y, c1.y);
                STE1(rB[dc].z, c1.z); STE1(rB[dc].w, c1.w);
            }
        }
        if (q == Q - 1) {                         // write final residual once
            float* rrow = ws + WS_RES + (gT + t0 + myTok) * CD + l4 * 8;
#pragma unroll
            for (int dc = 0; dc < 8; dc++) {
                *(float4*)(rrow + dc * 32)     = rA[dc];
                *(float4*)(rrow + dc * 32 + 4) = rB[dc];
            }
        }

        // ---- deterministic loss partial (f64) ----
#pragma unroll
        for (int m = 1; m < 64; m <<= 1) lacc += __shfl_xor(lacc, m, 64);
        __syncthreads();
        if (lane == 0) lredD[wv] = lacc;
        __syncthreads();
        if (tid == 0)
            lpD[((size_t)g * Q + q) * 256 + blockIdx.x] =
                (((lredD[0] + lredD[1]) + (lredD[2] + lredD[3])) +
                 ((lredD[4] + lredD[5]) + (lredD[6] + lredD[7])));
        __syncthreads();                          // protects cnS/lredD for next q
    }
}

// ---------------- K4: output projection out = (h - res) @ Wout_g^T + bout ----------------
__global__ __launch_bounds__(256) void k_proj_out(const float* __restrict__ ws,
                                                  const float* __restrict__ Wout,
                                                  const float* __restrict__ bout,
                                                  float* __restrict__ out) {
    __shared__ float As[32][65];
    __shared__ float Bs[32][65];
    const int g  = blockIdx.z;
    const int t0 = blockIdx.x * 64;
    const int d0 = blockIdx.y * 64;
    const int tid = threadIdx.x;
    const int tx = tid & 15, ty = tid >> 4;
    float acc[4][4] = {};
    const float* Ah = ws + WS_H + ((size_t)g * T + t0) * CD;
    const float* Ar = ws + WS_RES + ((size_t)g * T + t0) * CD;
    const float* Bb = Wout + (size_t)g * DG * CD + (size_t)d0 * CD;

    for (int k0 = 0; k0 < CD; k0 += 32) {
        __syncthreads();
#pragma unroll
        for (int j = 0; j < 8; j++) {
            int lin = j * 256 + tid;
            int k = lin & 31, r = lin >> 5;
            size_t o = (size_t)r * CD + k0 + k;
            As[k][r] = Ah[o] - Ar[o];            // qout = h - res_final
            Bs[k][r] = Bb[o];
        }
        __syncthreads();
#pragma unroll
        for (int k = 0; k < 32; k++) {
            float a[4], b[4];
#pragma unroll
            for (int i = 0; i < 4; i++) a[i] = As[k][ty + 16 * i];
#pragma unroll
            for (int j = 0; j < 4; j++) b[j] = Bs[k][tx + 16 * j];
#pragma unroll
            for (int i = 0; i < 4; i++)
#pragma unroll
                for (int j = 0; j < 4; j++) acc[i][j] = fmaf(a[i], b[j], acc[i][j]);
        }
    }
#pragma unroll
    for (int i = 0; i < 4; i++) {
        int t = t0 + ty + 16 * i;
#pragma unroll
        for (int j = 0; j < 4; j++) {
            int d = d0 + tx + 16 * j;
            out[(size_t)t * DIMV + (size_t)g * DG + d] = acc[i][j] + bout[g * DG + d];
        }
    }
}

// ---------------- K5: deterministic loss reduction (f64 -> f32) ----------------
__global__ void k_loss(const float* __restrict__ ws, float* __restrict__ out) {
    int gq = blockIdx.x;
    const double* lpD = (const double*)(ws + WS_LPARTD);
    double v = lpD[(size_t)gq * 256 + threadIdx.x];
#pragma unroll
    for (int m = 1; m < 64; m <<= 1) v += __shfl_xor(v, m, 64);
    __shared__ double red[4];
    if ((threadIdx.x & 63) == 0) red[threadIdx.x >> 6] = v;
    __syncthreads();
    if (threadIdx.x == 0)
        out[OUT_LOSS + gq] =
            (float)(((red[0] + red[1]) + (red[2] + red[3])) * (1.0 / 8388608.0));
}

extern "C" void kernel_launch(void* const* d_in, const int* in_sizes, int n_in,
                              void* d_out, int out_size, void* d_ws, size_t ws_size,
                              hipStream_t stream) {
    const float* x    = (const float*)d_in[0];
    const float* Win  = (const float*)d_in[1];
    const float* bin  = (const float*)d_in[2];
    const float* Wout = (const float*)d_in[3];
    const float* bout = (const float*)d_in[4];
    const float* cb   = (const float*)d_in[5];
    float* out = (float*)d_out;
    float* ws  = (float*)d_ws;

    // bf16 hi/lo codebook scratch in the not-yet-written quantized region of
    // d_out: 2*G*Q*K*CD bf16 = 4.2M f32-equiv << 41.9M f32 region.
    short* scr = (short*)d_out;
    short* cbh = scr;
    short* cbl = scr + (size_t)G * Q * KCODES * CD;

    hipLaunchKernelGGL(k_norms,    dim3(64),          dim3(256), 0, stream, cb, ws);
    hipLaunchKernelGGL(k_split,    dim3(4096),        dim3(256), 0, stream, cb, cbh, cbl);
    hipLaunchKernelGGL(k_proj_in,  dim3(T/64, 4, G),  dim3(256), 0, stream, x, Win, bin, ws);
    hipLaunchKernelGGL(k_rvq,      dim3(T/TM, G),     dim3(512), 0, stream, cb, ws, out, cbh, cbl);
    hipLaunchKernelGGL(k_proj_out, dim3(T/64, 10, G), dim3(256), 0, stream, ws, Wout, bout, out);
    hipLaunchKernelGGL(k_loss,     dim3(16),          dim3(256), 0, stream, ws, out);
}

// Round 14
// 2457.337 us; speedup vs baseline: 1.1651x; 1.0092x over previous
//
#include <hip/hip_runtime.h>
#include <hip/hip_bf16.h>

// Grouped Residual VQ: G=2, Q=8, K=1024, CD=256, DIM=1280 (DG=640), T=32768.
//
// Round 14 = r13 (register-resident residual) + CHEAP REFINEMENT:
// main scan tracks top-3 values + top-2 indices (total order, first-index
// ties). Flagged tokens (gap < EPS) get an exact f64 score for just the top-2
// candidates (parallel, register-resident residual, 2 rows instead of 1024);
// winner accepted iff provably below every f32-rank>=3 code (tv3 - ERRB).
// Rare uncertain cases fall back to the old serial full f64 scan.

#define G 2
#define Q 8
#define KCODES 1024
#define CD 256
#define DIMV 1280
#define DG 640
#define T 32768
#define TM 128

#define WS_H      ((size_t)0)
#define WS_RES    (WS_H + (size_t)G*T*CD)
#define WS_CNORM  (WS_RES + (size_t)G*T*CD)
#define WS_CN64   (WS_CNORM + (size_t)G*Q*KCODES)
#define WS_LPARTD (WS_CN64 + (size_t)2*G*Q*KCODES)

#define OUT_IDX   ((size_t)T*DIMV)
#define OUT_LOSS  (OUT_IDX + (size_t)G*T*Q)

#define EPS_REFINE 2e-3f
#define ERRB 1e-3

typedef __attribute__((ext_vector_type(8))) short s16x8;
typedef __attribute__((ext_vector_type(4))) float f32x4;

static __device__ __forceinline__ unsigned short f2bf(float v) {
    __hip_bfloat16 b = __float2bfloat16(v);
    return *(unsigned short*)&b;
}
static __device__ __forceinline__ float bf2f(unsigned short u) {
    __hip_bfloat16 b = *(__hip_bfloat16*)&u;
    return __bfloat162float(b);
}

static __device__ __forceinline__ void gl_lds16(const void* g, void* l) {
    __builtin_amdgcn_global_load_lds(
        (const __attribute__((address_space(1))) unsigned int*)g,
        (__attribute__((address_space(3))) unsigned int*)l, 16, 0, 0);
}

__device__ __forceinline__ float np_half_sumsq(const float4* __restrict__ p) {
    float4 a = p[0], b = p[1];
    float r0=a.x*a.x, r1=a.y*a.y, r2=a.z*a.z, r3=a.w*a.w;
    float r4=b.x*b.x, r5=b.y*b.y, r6=b.z*b.z, r7=b.w*b.w;
#pragma unroll
    for (int i = 1; i < 16; i++) {
        a = p[2*i]; b = p[2*i+1];
        r0 += a.x*a.x; r1 += a.y*a.y; r2 += a.z*a.z; r3 += a.w*a.w;
        r4 += b.x*b.x; r5 += b.y*b.y; r6 += b.z*b.z; r7 += b.w*b.w;
    }
    return ((r0+r1)+(r2+r3)) + ((r4+r5)+(r6+r7));
}

// ---------------- K1: codebook norms (f32 + exact f64) ----------------
__global__ void k_norms(const float* __restrict__ cb, float* __restrict__ ws) {
    int r = blockIdx.x * 256 + threadIdx.x;
    const float4* row = (const float4*)(cb + (size_t)r * CD);
    ws[WS_CNORM + r] = np_half_sumsq(row) + np_half_sumsq(row + 32);
    double s0=0, s1=0, s2=0, s3=0;
#pragma unroll 8
    for (int e = 0; e < 64; e++) {
        float4 v = row[e];
        s0 = fma((double)v.x,(double)v.x,s0); s1 = fma((double)v.y,(double)v.y,s1);
        s2 = fma((double)v.z,(double)v.z,s2); s3 = fma((double)v.w,(double)v.w,s3);
    }
    ((double*)(ws + WS_CN64))[r] = (s0+s1)+(s2+s3);
}

// ---------------- K1b: codebook bf16 hi/lo split ----------------
__global__ void k_split(const float* __restrict__ cb, short* __restrict__ cbh,
                        short* __restrict__ cbl) {
    size_t i = ((size_t)blockIdx.x * 256 + threadIdx.x) * 4;
    float4 v = *(const float4*)(cb + i);
    unsigned short h0=f2bf(v.x), h1=f2bf(v.y), h2=f2bf(v.z), h3=f2bf(v.w);
    *(short4*)(cbh + i) = make_short4((short)h0,(short)h1,(short)h2,(short)h3);
    *(short4*)(cbl + i) = make_short4((short)f2bf(v.x - bf2f(h0)), (short)f2bf(v.y - bf2f(h1)),
                                      (short)f2bf(v.z - bf2f(h2)), (short)f2bf(v.w - bf2f(h3)));
}

// ---------------- K2: input projection h = x_g @ Win_g^T + bin ----------------
__global__ __launch_bounds__(256) void k_proj_in(const float* __restrict__ x,
                                                 const float* __restrict__ Win,
                                                 const float* __restrict__ bin,
                                                 float* __restrict__ ws) {
    __shared__ float As[32][65];
    __shared__ float Bs[32][65];
    const int g  = blockIdx.z;
    const int t0 = blockIdx.x * 64;
    const int c0 = blockIdx.y * 64;
    const int tid = threadIdx.x;
    const int tx = tid & 15, ty = tid >> 4;
    float acc[4][4] = {};
    const float* Ab = x + (size_t)t0 * DIMV + (size_t)g * DG;
    const float* Bb = Win + (size_t)g * CD * DG + (size_t)c0 * DG;

    for (int k0 = 0; k0 < DG; k0 += 32) {
        __syncthreads();
#pragma unroll
        for (int j = 0; j < 8; j++) {
            int lin = j * 256 + tid;
            int k = lin & 31, r = lin >> 5;
            As[k][r] = Ab[(size_t)r * DIMV + k0 + k];
            Bs[k][r] = Bb[(size_t)r * DG + k0 + k];
        }
        __syncthreads();
#pragma unroll
        for (int k = 0; k < 32; k++) {
            float a[4], b[4];
#pragma unroll
            for (int i = 0; i < 4; i++) a[i] = As[k][ty + 16 * i];
#pragma unroll
            for (int j = 0; j < 4; j++) b[j] = Bs[k][tx + 16 * j];
#pragma unroll
            for (int i = 0; i < 4; i++)
#pragma unroll
                for (int j = 0; j < 4; j++) acc[i][j] = fmaf(a[i], b[j], acc[i][j]);
        }
    }
#pragma unroll
    for (int i = 0; i < 4; i++) {
        int t = t0 + ty + 16 * i;
        float* hrow = ws + WS_H + ((size_t)g * T + t) * CD;
#pragma unroll
        for (int j = 0; j < 4; j++) {
            int c = c0 + tx + 16 * j;
            hrow[c] = acc[i][j] + bin[g * CD + c];
        }
    }
}

// ---------------- K3: fused ResidualVQ (reg-resident residual, cheap refine) ----------------
#define STE1(rv, cv) { float tt_ = __fsub_rn((cv), (rv)); float qq_ = __fadd_rn((rv), tt_); \
                       float rr_ = __fsub_rn((rv), qq_); lacc += (double)rr_ * rr_; (rv) = rr_; }

__global__ __launch_bounds__(512, 2) void k_rvq(const float* __restrict__ cb,
                                                float* __restrict__ ws,
                                                float* __restrict__ out,
                                                const short* __restrict__ cbh,
                                                const short* __restrict__ cbl) {
    __shared__ s16x8 CbV[2][4096];               // 128 KB codebook window
    __shared__ float cnS[KCODES];                // 4 KB
    __shared__ __align__(16) float refS[8][256]; // 8 KB per-wave refinement scratch
    __shared__ double lredD[8];

    const int g  = blockIdx.y;
    const int t0 = blockIdx.x * TM;
    const int tid = threadIdx.x;
    const int lane = tid & 63, l15 = lane & 15, l4 = lane >> 4;
    const int wv = tid >> 6;
    const size_t gT = (size_t)g * T;
    const int myTok = wv * 16 + l15;
    const float* cng = ws + WS_CNORM + (size_t)g * Q * KCODES;
    double* lpD = (double*)(ws + WS_LPARTD);

    // codebook staging geometry: 8 gl_lds/thread/chunk
    int cpl[8], coff[8];
#pragma unroll
    for (int k = 0; k < 8; k++) {
        int u = (wv * 8 + k) * 64 + lane;        // 0..4095
        cpl[k] = u >> 11;
        int rem = u & 2047;
        int dcx = rem >> 8, ku = (rem >> 6) & 3, code = rem & 63;
        coff[k] = code * CD + dcx * 32 + ku * 8;
    }

    // ---- residual (f32) lives in registers for the whole kernel ----
    float4 rA[8], rB[8];
    {
        const float* hrow = ws + WS_H + (gT + t0 + myTok) * CD + l4 * 8;
#pragma unroll
        for (int dc = 0; dc < 8; dc++) {
            rA[dc] = *(const float4*)(hrow + dc * 32);
            rB[dc] = *(const float4*)(hrow + dc * 32 + 4);
        }
    }

    for (int q = 0; q < Q; q++) {
        const float* cnq = cng + (size_t)q * KCODES;
        const double* cn64q = (const double*)(ws + WS_CN64) + ((size_t)g * Q + q) * KCODES;
        const float* cqb = cb + ((size_t)g * Q + q) * KCODES * CD;
        const short* cbhq = cbh + ((size_t)g * Q + q) * KCODES * CD;
        const short* cblq = cbl + ((size_t)g * Q + q) * KCODES * CD;

        cnS[tid] = cnq[tid];
        cnS[512 + tid] = cnq[512 + tid];

        // ---- split register residual to bf16 hi/lo fragments (pure VALU) ----
        s16x8 fh[8], fl[8];
#pragma unroll
        for (int dc = 0; dc < 8; dc++) {
            float v[8] = {rA[dc].x, rA[dc].y, rA[dc].z, rA[dc].w,
                          rB[dc].x, rB[dc].y, rB[dc].z, rB[dc].w};
            s16x8 th, tl;
#pragma unroll
            for (int e = 0; e < 8; e++) {
                unsigned short hb = f2bf(v[e]);
                th[e] = (short)hb;
                tl[e] = (short)f2bf(v[e] - bf2f(hb));
            }
            fh[dc] = th; fl[dc] = tl;
        }

        // stage chunk 0 into buf 0
#pragma unroll
        for (int k = 0; k < 8; k++)
            gl_lds16((cpl[k] ? cblq : cbhq) + coff[k], &CbV[0][(wv * 8 + k) * 64]);
        __syncthreads();

        // top-3 values + top-2 indices (total order: value, then index)
        float tv1 = 3.4e38f, tv2 = 3.4e38f, tv3 = 3.4e38f;
        int   tix = 0x7fffffff, tix2 = 0x7fffffff;
        f32x4 acc[4];
#pragma unroll
        for (int t = 0; t < 4; t++) acc[t] = (f32x4){0.f, 0.f, 0.f, 0.f};

        for (int cc = 0; cc < 16; cc++) {
            __builtin_amdgcn_s_barrier();
            if (cc + 1 < 16) {
                const size_t add = (size_t)(cc + 1) * 64 * CD;
#pragma unroll
                for (int k = 0; k < 8; k++)
                    gl_lds16((cpl[k] ? cblq : cbhq) + coff[k] + add,
                             &CbV[(cc + 1) & 1][(wv * 8 + k) * 64]);
                asm volatile("s_waitcnt vmcnt(8)" ::: "memory");
            } else {
                asm volatile("s_waitcnt vmcnt(0)" ::: "memory");
            }
            __builtin_amdgcn_s_barrier();
            __builtin_amdgcn_sched_barrier(0);

            const int buf = cc & 1;
#pragma unroll
            for (int dc = 0; dc < 8; dc++) {
#pragma unroll
                for (int t = 0; t < 4; t++) {
                    int idx = dc * 256 + l4 * 64 + t * 16 + l15;
                    s16x8 ch = CbV[buf][idx];
                    s16x8 cl2 = CbV[buf][2048 + idx];
                    acc[t] = __builtin_amdgcn_mfma_f32_16x16x32_bf16(ch, fh[dc], acc[t], 0, 0, 0);
                    acc[t] = __builtin_amdgcn_mfma_f32_16x16x32_bf16(ch, fl[dc], acc[t], 0, 0, 0);
                    acc[t] = __builtin_amdgcn_mfma_f32_16x16x32_bf16(cl2, fh[dc], acc[t], 0, 0, 0);
                }
            }
            // score chunk cc (candidates arrive in ascending c within each lane)
#pragma unroll
            for (int t = 0; t < 4; t++)
#pragma unroll
                for (int r = 0; r < 4; r++) {
                    int c = cc * 64 + t * 16 + l4 * 4 + r;
                    float vv = fmaf(-2.f, acc[t][r], cnS[c]);
                    if (vv < tv1)      { tv3 = tv2; tv2 = tv1; tix2 = tix; tv1 = vv; tix = c; }
                    else if (vv < tv2) { tv3 = tv2; tv2 = vv; tix2 = c; }
                    else if (vv < tv3) { tv3 = vv; }
                }
#pragma unroll
            for (int t = 0; t < 4; t++) acc[t] = (f32x4){0.f, 0.f, 0.f, 0.f};
        }

        // ---- merge the 4 same-token lanes: sorted-triple merge (strides 16,32) ----
#pragma unroll
        for (int m = 16; m < 64; m <<= 1) {
            float b1 = __shfl_xor(tv1, m, 64);
            int   bi1 = __shfl_xor(tix, m, 64);
            float b2 = __shfl_xor(tv2, m, 64);
            int   bi2 = __shfl_xor(tix2, m, 64);
            float b3 = __shfl_xor(tv3, m, 64);
            float n1, n2, n3; int ni1, ni2;
            bool bf = (b1 < tv1) || (b1 == tv1 && bi1 < tix);
            if (bf) {
                n1 = b1; ni1 = bi1;
                bool af = (tv1 < b2) || (tv1 == b2 && tix < bi2);
                if (af) { n2 = tv1; ni2 = tix; n3 = fminf(tv2, b2); }
                else    { n2 = b2;  ni2 = bi2; n3 = fminf(tv1, b3); }
            } else {
                n1 = tv1; ni1 = tix;
                bool bs = (b1 < tv2) || (b1 == tv2 && bi1 < tix2);
                if (bs) { n2 = b1;  ni2 = bi1;  n3 = fminf(tv2, b2); }
                else    { n2 = tv2; ni2 = tix2; n3 = fminf(b1, tv3); }
            }
            tv1 = n1; tix = ni1; tv2 = n2; tix2 = ni2; tv3 = n3;
        }

        // ---- cheap exact refinement: f64 scores of top-2 only ----
        int besti = tix;
        bool flag = (tv2 - tv1 < EPS_REFINE);
        bool need_full = false;
        if (__any(flag)) {
            const float* c1r = cqb + (size_t)tix  * CD + l4 * 8;
            const float* c2r = cqb + (size_t)tix2 * CD + l4 * 8;
            double d1 = 0.0, d2 = 0.0;
#pragma unroll
            for (int dc = 0; dc < 8; dc++) {
                float4 p0 = *(const float4*)(c1r + dc * 32);
                float4 p1 = *(const float4*)(c1r + dc * 32 + 4);
                float4 q0 = *(const float4*)(c2r + dc * 32);
                float4 q1 = *(const float4*)(c2r + dc * 32 + 4);
                d1 = fma((double)rA[dc].x,(double)p0.x,d1); d1 = fma((double)rA[dc].y,(double)p0.y,d1);
                d1 = fma((double)rA[dc].z,(double)p0.z,d1); d1 = fma((double)rA[dc].w,(double)p0.w,d1);
                d1 = fma((double)rB[dc].x,(double)p1.x,d1); d1 = fma((double)rB[dc].y,(double)p1.y,d1);
                d1 = fma((double)rB[dc].z,(double)p1.z,d1); d1 = fma((double)rB[dc].w,(double)p1.w,d1);
                d2 = fma((double)rA[dc].x,(double)q0.x,d2); d2 = fma((double)rA[dc].y,(double)q0.y,d2);
                d2 = fma((double)rA[dc].z,(double)q0.z,d2); d2 = fma((double)rA[dc].w,(double)q0.w,d2);
                d2 = fma((double)rB[dc].x,(double)q1.x,d2); d2 = fma((double)rB[dc].y,(double)q1.y,d2);
                d2 = fma((double)rB[dc].z,(double)q1.z,d2); d2 = fma((double)rB[dc].w,(double)q1.w,d2);
            }
#pragma unroll
            for (int m = 16; m < 64; m <<= 1) {
                d1 += __shfl_xor(d1, m, 64);
                d2 += __shfl_xor(d2, m, 64);
            }
            double s1 = fma(-2.0, d1, cn64q[tix]);
            double s2 = fma(-2.0, d2, cn64q[tix2]);
            bool c2wins = (s2 < s1) || (s2 == s1 && tix2 < tix);
            double swin = c2wins ? s2 : s1;
            int    iwin = c2wins ? tix2 : tix;
            if (flag) besti = iwin;
            need_full = flag && !(swin < (double)tv3 - ERRB);
        }

        // ---- rare fallback: serial full f64 scan ----
        unsigned long long flg = __ballot(need_full) & 0xFFFFull;
        while (flg) {
            int l = __builtin_ctzll(flg); flg &= flg - 1;
            if (l15 == l) {
#pragma unroll
                for (int dc = 0; dc < 8; dc++) {
                    *(float4*)(&refS[wv][dc * 32 + l4 * 8])     = rA[dc];
                    *(float4*)(&refS[wv][dc * 32 + l4 * 8 + 4]) = rB[dc];
                }
            }
            asm volatile("s_waitcnt lgkmcnt(0)" ::: "memory");
            __builtin_amdgcn_sched_barrier(0);
            const float4* rf4 = (const float4*)(&refS[wv][0]);
            double bv = 1e300; int bi = 0x7fffffff;
            for (int c = lane; c < KCODES; c += 64) {
                const float4* cp4 = (const float4*)(cqb + (size_t)c * CD);
                double a0=0, a1=0, a2=0, a3=0;
#pragma unroll 4
                for (int e = 0; e < 64; e++) {
                    float4 cv = cp4[e], rv = rf4[e];
                    a0 = fma((double)rv.x,(double)cv.x,a0); a1 = fma((double)rv.y,(double)cv.y,a1);
                    a2 = fma((double)rv.z,(double)cv.z,a2); a3 = fma((double)rv.w,(double)cv.w,a3);
                }
                double dd = fma(-2.0, (a0+a1)+(a2+a3), cn64q[c]);
                if (dd < bv) { bv = dd; bi = c; }
            }
#pragma unroll
            for (int m = 1; m < 64; m <<= 1) {
                double ov = __shfl_xor(bv, m, 64);
                int    oi = __shfl_xor(bi, m, 64);
                if (ov < bv || (ov == bv && oi < bi)) { bv = ov; bi = oi; }
            }
            if (l15 == l) besti = bi;
            asm volatile("s_waitcnt lgkmcnt(0)" ::: "memory");
        }

        // ---- idx out (lane<16 holds token wv*16+lane) ----
        if (lane < 16)
            out[OUT_IDX + (gT + t0 + wv * 16 + lane) * Q + q] = (float)besti;

        // ---- STE update in registers from gathered code row ----
        double lacc = 0.0;
        {
            const float* crow = cqb + (size_t)besti * CD + l4 * 8;
#pragma unroll
            for (int dc = 0; dc < 8; dc++) {
                float4 c0 = *(const float4*)(crow + dc * 32);
                float4 c1 = *(const float4*)(crow + dc * 32 + 4);
                STE1(rA[dc].x, c0.x); STE1(rA[dc].y, c0.y);
                STE1(rA[dc].z, c0.z); STE1(rA[dc].w, c0.w);
                STE1(rB[dc].x, c1.x); STE1(rB[dc].y, c1.y);
                STE1(rB[dc].z, c1.z); STE1(rB[dc].w, c1.w);
            }
        }
        if (q == Q - 1) {
            float* rrow = ws + WS_RES + (gT + t0 + myTok) * CD + l4 * 8;
#pragma unroll
            for (int dc = 0; dc < 8; dc++) {
                *(float4*)(rrow + dc * 32)     = rA[dc];
                *(float4*)(rrow + dc * 32 + 4) = rB[dc];
            }
        }

        // ---- deterministic loss partial (f64) ----
#pragma unroll
        for (int m = 1; m < 64; m <<= 1) lacc += __shfl_xor(lacc, m, 64);
        __syncthreads();
        if (lane == 0) lredD[wv] = lacc;
        __syncthreads();
        if (tid == 0)
            lpD[((size_t)g * Q + q) * 256 + blockIdx.x] =
                (((lredD[0] + lredD[1]) + (lredD[2] + lredD[3])) +
                 ((lredD[4] + lredD[5]) + (lredD[6] + lredD[7])));
        __syncthreads();
    }
}

// ---------------- K4: output projection out = (h - res) @ Wout_g^T + bout ----------------
__global__ __launch_bounds__(256) void k_proj_out(const float* __restrict__ ws,
                                                  const float* __restrict__ Wout,
                                                  const float* __restrict__ bout,
                                                  float* __restrict__ out) {
    __shared__ float As[32][65];
    __shared__ float Bs[32][65];
    const int g  = blockIdx.z;
    const int t0 = blockIdx.x * 64;
    const int d0 = blockIdx.y * 64;
    const int tid = threadIdx.x;
    const int tx = tid & 15, ty = tid >> 4;
    float acc[4][4] = {};
    const float* Ah = ws + WS_H + ((size_t)g * T + t0) * CD;
    const float* Ar = ws + WS_RES + ((size_t)g * T + t0) * CD;
    const float* Bb = Wout + (size_t)g * DG * CD + (size_t)d0 * CD;

    for (int k0 = 0; k0 < CD; k0 += 32) {
        __syncthreads();
#pragma unroll
        for (int j = 0; j < 8; j++) {
            int lin = j * 256 + tid;
            int k = lin & 31, r = lin >> 5;
            size_t o = (size_t)r * CD + k0 + k;
            As[k][r] = Ah[o] - Ar[o];            // qout = h - res_final
            Bs[k][r] = Bb[o];
        }
        __syncthreads();
#pragma unroll
        for (int k = 0; k < 32; k++) {
            float a[4], b[4];
#pragma unroll
            for (int i = 0; i < 4; i++) a[i] = As[k][ty + 16 * i];
#pragma unroll
            for (int j = 0; j < 4; j++) b[j] = Bs[k][tx + 16 * j];
#pragma unroll
            for (int i = 0; i < 4; i++)
#pragma unroll
                for (int j = 0; j < 4; j++) acc[i][j] = fmaf(a[i], b[j], acc[i][j]);
        }
    }
#pragma unroll
    for (int i = 0; i < 4; i++) {
        int t = t0 + ty + 16 * i;
#pragma unroll
        for (int j = 0; j < 4; j++) {
            int d = d0 + tx + 16 * j;
            out[(size_t)t * DIMV + (size_t)g * DG + d] = acc[i][j] + bout[g * DG + d];
        }
    }
}

// ---------------- K5: deterministic loss reduction (f64 -> f32) ----------------
__global__ void k_loss(const float* __restrict__ ws, float* __restrict__ out) {
    int gq = blockIdx.x;
    const double* lpD = (const double*)(ws + WS_LPARTD);
    double v = lpD[(size_t)gq * 256 + threadIdx.x];
#pragma unroll
    for (int m = 1; m < 64; m <<= 1) v += __shfl_xor(v, m, 64);
    __shared__ double red[4];
    if ((threadIdx.x & 63) == 0) red[threadIdx.x >> 6] = v;
    __syncthreads();
    if (threadIdx.x == 0)
        out[OUT_LOSS + gq] =
            (float)(((red[0] + red[1]) + (red[2] + red[3])) * (1.0 / 8388608.0));
}

extern "C" void kernel_launch(void* const* d_in, const int* in_sizes, int n_in,
                              void* d_out, int out_size, void* d_ws, size_t ws_size,
                              hipStream_t stream) {
    const float* x    = (const float*)d_in[0];
    const float* Win  = (const float*)d_in[1];
    const float* bin  = (const float*)d_in[2];
    const float* Wout = (const float*)d_in[3];
    const float* bout = (const float*)d_in[4];
    const float* cb   = (const float*)d_in[5];
    float* out = (float*)d_out;
    float* ws  = (float*)d_ws;

    // bf16 hi/lo codebook scratch in the not-yet-written quantized region of
    // d_out: 2*G*Q*K*CD bf16 = 4.2M f32-equiv << 41.9M f32 region.
    short* scr = (short*)d_out;
    short* cbh = scr;
    short* cbl = scr + (size_t)G * Q * KCODES * CD;

    hipLaunchKernelGGL(k_norms,    dim3(64),          dim3(256), 0, stream, cb, ws);
    hipLaunchKernelGGL(k_split,    dim3(4096),        dim3(256), 0, stream, cb, cbh, cbl);
    hipLaunchKernelGGL(k_proj_in,  dim3(T/64, 4, G),  dim3(256), 0, stream, x, Win, bin, ws);
    hipLaunchKernelGGL(k_rvq,      dim3(T/TM, G),     dim3(512), 0, stream, cb, ws, out, cbh, cbl);
    hipLaunchKernelGGL(k_proj_out, dim3(T/64, 10, G), dim3(256), 0, stream, ws, Wout, bout, out);
    hipLaunchKernelGGL(k_loss,     dim3(16),          dim3(256), 0, stream, ws, out);
}

// Round 15
// 2106.662 us; speedup vs baseline: 1.3590x; 1.1665x over previous
//
#include <hip/hip_runtime.h>
#include <hip/hip_bf16.h>

// Grouped Residual VQ: G=2, Q=8, K=1024, CD=256, DIM=1280 (DG=640), T=32768.
//
// Round 15 = r14 + COALESCED codebook staging:
// LDS chunk layout changed from code-fastest to [plane][code][dim-unit] with
// XOR-8 swizzle (u_phys = u_log ^ (code&7)), applied as pre-swizzled GLOBAL
// source (permutes within 128B octets -> stays coalesced) + matching XOR on
// the ds_read index. Each gl_lds wave-instruction now reads 1 KB contiguous
// (2 adjacent 512B code rows) instead of 64 lines at 512B stride.

#define G 2
#define Q 8
#define KCODES 1024
#define CD 256
#define DIMV 1280
#define DG 640
#define T 32768
#define TM 128

#define WS_H      ((size_t)0)
#define WS_RES    (WS_H + (size_t)G*T*CD)
#define WS_CNORM  (WS_RES + (size_t)G*T*CD)
#define WS_CN64   (WS_CNORM + (size_t)G*Q*KCODES)
#define WS_LPARTD (WS_CN64 + (size_t)2*G*Q*KCODES)

#define OUT_IDX   ((size_t)T*DIMV)
#define OUT_LOSS  (OUT_IDX + (size_t)G*T*Q)

#define EPS_REFINE 2e-3f
#define ERRB 1e-3

typedef __attribute__((ext_vector_type(8))) short s16x8;
typedef __attribute__((ext_vector_type(4))) float f32x4;

static __device__ __forceinline__ unsigned short f2bf(float v) {
    __hip_bfloat16 b = __float2bfloat16(v);
    return *(unsigned short*)&b;
}
static __device__ __forceinline__ float bf2f(unsigned short u) {
    __hip_bfloat16 b = *(__hip_bfloat16*)&u;
    return __bfloat162float(b);
}

static __device__ __forceinline__ void gl_lds16(const void* g, void* l) {
    __builtin_amdgcn_global_load_lds(
        (const __attribute__((address_space(1))) unsigned int*)g,
        (__attribute__((address_space(3))) unsigned int*)l, 16, 0, 0);
}

__device__ __forceinline__ float np_half_sumsq(const float4* __restrict__ p) {
    float4 a = p[0], b = p[1];
    float r0=a.x*a.x, r1=a.y*a.y, r2=a.z*a.z, r3=a.w*a.w;
    float r4=b.x*b.x, r5=b.y*b.y, r6=b.z*b.z, r7=b.w*b.w;
#pragma unroll
    for (int i = 1; i < 16; i++) {
        a = p[2*i]; b = p[2*i+1];
        r0 += a.x*a.x; r1 += a.y*a.y; r2 += a.z*a.z; r3 += a.w*a.w;
        r4 += b.x*b.x; r5 += b.y*b.y; r6 += b.z*b.z; r7 += b.w*b.w;
    }
    return ((r0+r1)+(r2+r3)) + ((r4+r5)+(r6+r7));
}

// ---------------- K1: codebook norms (f32 + exact f64) ----------------
__global__ void k_norms(const float* __restrict__ cb, float* __restrict__ ws) {
    int r = blockIdx.x * 256 + threadIdx.x;
    const float4* row = (const float4*)(cb + (size_t)r * CD);
    ws[WS_CNORM + r] = np_half_sumsq(row) + np_half_sumsq(row + 32);
    double s0=0, s1=0, s2=0, s3=0;
#pragma unroll 8
    for (int e = 0; e < 64; e++) {
        float4 v = row[e];
        s0 = fma((double)v.x,(double)v.x,s0); s1 = fma((double)v.y,(double)v.y,s1);
        s2 = fma((double)v.z,(double)v.z,s2); s3 = fma((double)v.w,(double)v.w,s3);
    }
    ((double*)(ws + WS_CN64))[r] = (s0+s1)+(s2+s3);
}

// ---------------- K1b: codebook bf16 hi/lo split ----------------
__global__ void k_split(const float* __restrict__ cb, short* __restrict__ cbh,
                        short* __restrict__ cbl) {
    size_t i = ((size_t)blockIdx.x * 256 + threadIdx.x) * 4;
    float4 v = *(const float4*)(cb + i);
    unsigned short h0=f2bf(v.x), h1=f2bf(v.y), h2=f2bf(v.z), h3=f2bf(v.w);
    *(short4*)(cbh + i) = make_short4((short)h0,(short)h1,(short)h2,(short)h3);
    *(short4*)(cbl + i) = make_short4((short)f2bf(v.x - bf2f(h0)), (short)f2bf(v.y - bf2f(h1)),
                                      (short)f2bf(v.z - bf2f(h2)), (short)f2bf(v.w - bf2f(h3)));
}

// ---------------- K2: input projection h = x_g @ Win_g^T + bin ----------------
__global__ __launch_bounds__(256) void k_proj_in(const float* __restrict__ x,
                                                 const float* __restrict__ Win,
                                                 const float* __restrict__ bin,
                                                 float* __restrict__ ws) {
    __shared__ float As[32][65];
    __shared__ float Bs[32][65];
    const int g  = blockIdx.z;
    const int t0 = blockIdx.x * 64;
    const int c0 = blockIdx.y * 64;
    const int tid = threadIdx.x;
    const int tx = tid & 15, ty = tid >> 4;
    float acc[4][4] = {};
    const float* Ab = x + (size_t)t0 * DIMV + (size_t)g * DG;
    const float* Bb = Win + (size_t)g * CD * DG + (size_t)c0 * DG;

    for (int k0 = 0; k0 < DG; k0 += 32) {
        __syncthreads();
#pragma unroll
        for (int j = 0; j < 8; j++) {
            int lin = j * 256 + tid;
            int k = lin & 31, r = lin >> 5;
            As[k][r] = Ab[(size_t)r * DIMV + k0 + k];
            Bs[k][r] = Bb[(size_t)r * DG + k0 + k];
        }
        __syncthreads();
#pragma unroll
        for (int k = 0; k < 32; k++) {
            float a[4], b[4];
#pragma unroll
            for (int i = 0; i < 4; i++) a[i] = As[k][ty + 16 * i];
#pragma unroll
            for (int j = 0; j < 4; j++) b[j] = Bs[k][tx + 16 * j];
#pragma unroll
            for (int i = 0; i < 4; i++)
#pragma unroll
                for (int j = 0; j < 4; j++) acc[i][j] = fmaf(a[i], b[j], acc[i][j]);
        }
    }
#pragma unroll
    for (int i = 0; i < 4; i++) {
        int t = t0 + ty + 16 * i;
        float* hrow = ws + WS_H + ((size_t)g * T + t) * CD;
#pragma unroll
        for (int j = 0; j < 4; j++) {
            int c = c0 + tx + 16 * j;
            hrow[c] = acc[i][j] + bin[g * CD + c];
        }
    }
}

// ---------------- K3: fused ResidualVQ (reg-resident residual, coalesced staging) ----------------
#define STE1(rv, cv) { float tt_ = __fsub_rn((cv), (rv)); float qq_ = __fadd_rn((rv), tt_); \
                       float rr_ = __fsub_rn((rv), qq_); lacc += (double)rr_ * rr_; (rv) = rr_; }

__global__ __launch_bounds__(512, 2) void k_rvq(const float* __restrict__ cb,
                                                float* __restrict__ ws,
                                                float* __restrict__ out,
                                                const short* __restrict__ cbh,
                                                const short* __restrict__ cbl) {
    __shared__ s16x8 CbV[2][4096];               // 128 KB: n = pl*2048 + code*32 + u_phys
    __shared__ float cnS[KCODES];                // 4 KB
    __shared__ __align__(16) float refS[8][256]; // 8 KB per-wave refinement scratch
    __shared__ double lredD[8];

    const int g  = blockIdx.y;
    const int t0 = blockIdx.x * TM;
    const int tid = threadIdx.x;
    const int lane = tid & 63, l15 = lane & 15, l4 = lane >> 4;
    const int wv = tid >> 6;
    const size_t gT = (size_t)g * T;
    const int myTok = wv * 16 + l15;
    const float* cng = ws + WS_CNORM + (size_t)g * Q * KCODES;
    double* lpD = (double*)(ws + WS_LPARTD);

    // COALESCED staging geometry: load k covers linear LDS units
    // [(wv*8+k)*64, +64) = 2 adjacent code rows. Source pre-swizzled:
    // u_src = u_phys ^ (code&7) (permutes within 128B octets -> coalesced).
    int cpl[8], coff[8];
#pragma unroll
    for (int k = 0; k < 8; k++) {
        int n = (wv * 8 + k) * 64 + lane;        // 0..4095
        cpl[k] = n >> 11;
        int code = (n >> 5) & 63, u_phys = n & 31;
        int u_src = u_phys ^ (code & 7);
        coff[k] = code * CD + u_src * 8;         // shorts
    }

    // ---- residual (f32) lives in registers for the whole kernel ----
    float4 rA[8], rB[8];
    {
        const float* hrow = ws + WS_H + (gT + t0 + myTok) * CD + l4 * 8;
#pragma unroll
        for (int dc = 0; dc < 8; dc++) {
            rA[dc] = *(const float4*)(hrow + dc * 32);
            rB[dc] = *(const float4*)(hrow + dc * 32 + 4);
        }
    }

    for (int q = 0; q < Q; q++) {
        const float* cnq = cng + (size_t)q * KCODES;
        const double* cn64q = (const double*)(ws + WS_CN64) + ((size_t)g * Q + q) * KCODES;
        const float* cqb = cb + ((size_t)g * Q + q) * KCODES * CD;
        const short* cbhq = cbh + ((size_t)g * Q + q) * KCODES * CD;
        const short* cblq = cbl + ((size_t)g * Q + q) * KCODES * CD;

        cnS[tid] = cnq[tid];
        cnS[512 + tid] = cnq[512 + tid];

        // ---- split register residual to bf16 hi/lo fragments (pure VALU) ----
        s16x8 fh[8], fl[8];
#pragma unroll
        for (int dc = 0; dc < 8; dc++) {
            float v[8] = {rA[dc].x, rA[dc].y, rA[dc].z, rA[dc].w,
                          rB[dc].x, rB[dc].y, rB[dc].z, rB[dc].w};
            s16x8 th, tl;
#pragma unroll
            for (int e = 0; e < 8; e++) {
                unsigned short hb = f2bf(v[e]);
                th[e] = (short)hb;
                tl[e] = (short)f2bf(v[e] - bf2f(hb));
            }
            fh[dc] = th; fl[dc] = tl;
        }

        // stage chunk 0 into buf 0
#pragma unroll
        for (int k = 0; k < 8; k++)
            gl_lds16((cpl[k] ? cblq : cbhq) + coff[k], &CbV[0][(wv * 8 + k) * 64]);
        __syncthreads();

        // top-3 values + top-2 indices (total order: value, then index)
        float tv1 = 3.4e38f, tv2 = 3.4e38f, tv3 = 3.4e38f;
        int   tix = 0x7fffffff, tix2 = 0x7fffffff;
        f32x4 acc[4];
#pragma unroll
        for (int t = 0; t < 4; t++) acc[t] = (f32x4){0.f, 0.f, 0.f, 0.f};

        for (int cc = 0; cc < 16; cc++) {
            __builtin_amdgcn_s_barrier();
            if (cc + 1 < 16) {
                const size_t add = (size_t)(cc + 1) * 64 * CD;
#pragma unroll
                for (int k = 0; k < 8; k++)
                    gl_lds16((cpl[k] ? cblq : cbhq) + coff[k] + add,
                             &CbV[(cc + 1) & 1][(wv * 8 + k) * 64]);
                asm volatile("s_waitcnt vmcnt(8)" ::: "memory");
            } else {
                asm volatile("s_waitcnt vmcnt(0)" ::: "memory");
            }
            __builtin_amdgcn_s_barrier();
            __builtin_amdgcn_sched_barrier(0);

            const int buf = cc & 1;
#pragma unroll
            for (int dc = 0; dc < 8; dc++) {
#pragma unroll
                for (int t = 0; t < 4; t++) {
                    int code = t * 16 + l15;
                    int idx = code * 32 + ((dc * 4 + l4) ^ (code & 7));
                    s16x8 ch = CbV[buf][idx];
                    s16x8 cl2 = CbV[buf][2048 + idx];
                    acc[t] = __builtin_amdgcn_mfma_f32_16x16x32_bf16(ch, fh[dc], acc[t], 0, 0, 0);
                    acc[t] = __builtin_amdgcn_mfma_f32_16x16x32_bf16(ch, fl[dc], acc[t], 0, 0, 0);
                    acc[t] = __builtin_amdgcn_mfma_f32_16x16x32_bf16(cl2, fh[dc], acc[t], 0, 0, 0);
                }
            }
            // score chunk cc (candidates arrive in ascending c within each lane)
#pragma unroll
            for (int t = 0; t < 4; t++)
#pragma unroll
                for (int r = 0; r < 4; r++) {
                    int c = cc * 64 + t * 16 + l4 * 4 + r;
                    float vv = fmaf(-2.f, acc[t][r], cnS[c]);
                    if (vv < tv1)      { tv3 = tv2; tv2 = tv1; tix2 = tix; tv1 = vv; tix = c; }
                    else if (vv < tv2) { tv3 = tv2; tv2 = vv; tix2 = c; }
                    else if (vv < tv3) { tv3 = vv; }
                }
#pragma unroll
            for (int t = 0; t < 4; t++) acc[t] = (f32x4){0.f, 0.f, 0.f, 0.f};
        }

        // ---- merge the 4 same-token lanes: sorted-triple merge (strides 16,32) ----
#pragma unroll
        for (int m = 16; m < 64; m <<= 1) {
            float b1 = __shfl_xor(tv1, m, 64);
            int   bi1 = __shfl_xor(tix, m, 64);
            float b2 = __shfl_xor(tv2, m, 64);
            int   bi2 = __shfl_xor(tix2, m, 64);
            float b3 = __shfl_xor(tv3, m, 64);
            float n1, n2, n3; int ni1, ni2;
            bool bf = (b1 < tv1) || (b1 == tv1 && bi1 < tix);
            if (bf) {
                n1 = b1; ni1 = bi1;
                bool af = (tv1 < b2) || (tv1 == b2 && tix < bi2);
                if (af) { n2 = tv1; ni2 = tix; n3 = fminf(tv2, b2); }
                else    { n2 = b2;  ni2 = bi2; n3 = fminf(tv1, b3); }
            } else {
                n1 = tv1; ni1 = tix;
                bool bs = (b1 < tv2) || (b1 == tv2 && bi1 < tix2);
                if (bs) { n2 = b1;  ni2 = bi1;  n3 = fminf(tv2, b2); }
                else    { n2 = tv2; ni2 = tix2; n3 = fminf(b1, tv3); }
            }
            tv1 = n1; tix = ni1; tv2 = n2; tix2 = ni2; tv3 = n3;
        }

        // ---- cheap exact refinement: f64 scores of top-2 only ----
        int besti = tix;
        bool flag = (tv2 - tv1 < EPS_REFINE);
        bool need_full = false;
        if (__any(flag)) {
            const float* c1r = cqb + (size_t)tix  * CD + l4 * 8;
            const float* c2r = cqb + (size_t)tix2 * CD + l4 * 8;
            double d1 = 0.0, d2 = 0.0;
#pragma unroll
            for (int dc = 0; dc < 8; dc++) {
                float4 p0 = *(const float4*)(c1r + dc * 32);
                float4 p1 = *(const float4*)(c1r + dc * 32 + 4);
                float4 q0 = *(const float4*)(c2r + dc * 32);
                float4 q1 = *(const float4*)(c2r + dc * 32 + 4);
                d1 = fma((double)rA[dc].x,(double)p0.x,d1); d1 = fma((double)rA[dc].y,(double)p0.y,d1);
                d1 = fma((double)rA[dc].z,(double)p0.z,d1); d1 = fma((double)rA[dc].w,(double)p0.w,d1);
                d1 = fma((double)rB[dc].x,(double)p1.x,d1); d1 = fma((double)rB[dc].y,(double)p1.y,d1);
                d1 = fma((double)rB[dc].z,(double)p1.z,d1); d1 = fma((double)rB[dc].w,(double)p1.w,d1);
                d2 = fma((double)rA[dc].x,(double)q0.x,d2); d2 = fma((double)rA[dc].y,(double)q0.y,d2);
                d2 = fma((double)rA[dc].z,(double)q0.z,d2); d2 = fma((double)rA[dc].w,(double)q0.w,d2);
                d2 = fma((double)rB[dc].x,(double)q1.x,d2); d2 = fma((double)rB[dc].y,(double)q1.y,d2);
                d2 = fma((double)rB[dc].z,(double)q1.z,d2); d2 = fma((double)rB[dc].w,(double)q1.w,d2);
            }
#pragma unroll
            for (int m = 16; m < 64; m <<= 1) {
                d1 += __shfl_xor(d1, m, 64);
                d2 += __shfl_xor(d2, m, 64);
            }
            double s1 = fma(-2.0, d1, cn64q[tix]);
            double s2 = fma(-2.0, d2, cn64q[tix2]);
            bool c2wins = (s2 < s1) || (s2 == s1 && tix2 < tix);
            double swin = c2wins ? s2 : s1;
            int    iwin = c2wins ? tix2 : tix;
            if (flag) besti = iwin;
            need_full = flag && !(swin < (double)tv3 - ERRB);
        }

        // ---- rare fallback: serial full f64 scan ----
        unsigned long long flg = __ballot(need_full) & 0xFFFFull;
        while (flg) {
            int l = __builtin_ctzll(flg); flg &= flg - 1;
            if (l15 == l) {
#pragma unroll
                for (int dc = 0; dc < 8; dc++) {
                    *(float4*)(&refS[wv][dc * 32 + l4 * 8])     = rA[dc];
                    *(float4*)(&refS[wv][dc * 32 + l4 * 8 + 4]) = rB[dc];
                }
            }
            asm volatile("s_waitcnt lgkmcnt(0)" ::: "memory");
            __builtin_amdgcn_sched_barrier(0);
            const float4* rf4 = (const float4*)(&refS[wv][0]);
            double bv = 1e300; int bi = 0x7fffffff;
            for (int c = lane; c < KCODES; c += 64) {
                const float4* cp4 = (const float4*)(cqb + (size_t)c * CD);
                double a0=0, a1=0, a2=0, a3=0;
#pragma unroll 4
                for (int e = 0; e < 64; e++) {
                    float4 cv = cp4[e], rv = rf4[e];
                    a0 = fma((double)rv.x,(double)cv.x,a0); a1 = fma((double)rv.y,(double)cv.y,a1);
                    a2 = fma((double)rv.z,(double)cv.z,a2); a3 = fma((double)rv.w,(double)cv.w,a3);
                }
                double dd = fma(-2.0, (a0+a1)+(a2+a3), cn64q[c]);
                if (dd < bv) { bv = dd; bi = c; }
            }
#pragma unroll
            for (int m = 1; m < 64; m <<= 1) {
                double ov = __shfl_xor(bv, m, 64);
                int    oi = __shfl_xor(bi, m, 64);
                if (ov < bv || (ov == bv && oi < bi)) { bv = ov; bi = oi; }
            }
            if (l15 == l) besti = bi;
            asm volatile("s_waitcnt lgkmcnt(0)" ::: "memory");
        }

        // ---- idx out (lane<16 holds token wv*16+lane) ----
        if (lane < 16)
            out[OUT_IDX + (gT + t0 + wv * 16 + lane) * Q + q] = (float)besti;

        // ---- STE update in registers from gathered code row ----
        double lacc = 0.0;
        {
            const float* crow = cqb + (size_t)besti * CD + l4 * 8;
#pragma unroll
            for (int dc = 0; dc < 8; dc++) {
                float4 c0 = *(const float4*)(crow + dc * 32);
                float4 c1 = *(const float4*)(crow + dc * 32 + 4);
                STE1(rA[dc].x, c0.x); STE1(rA[dc].y, c0.y);
                STE1(rA[dc].z, c0.z); STE1(rA[dc].w, c0.w);
                STE1(rB[dc].x, c1.x); STE1(rB[dc].y, c1.y);
                STE1(rB[dc].z, c1.z); STE1(rB[dc].w, c1.w);
            }
        }
        if (q == Q - 1) {
            float* rrow = ws + WS_RES + (gT + t0 + myTok) * CD + l4 * 8;
#pragma unroll
            for (int dc = 0; dc < 8; dc++) {
                *(float4*)(rrow + dc * 32)     = rA[dc];
                *(float4*)(rrow + dc * 32 + 4) = rB[dc];
            }
        }

        // ---- deterministic loss partial (f64) ----
#pragma unroll
        for (int m = 1; m < 64; m <<= 1) lacc += __shfl_xor(lacc, m, 64);
        __syncthreads();
        if (lane == 0) lredD[wv] = lacc;
        __syncthreads();
        if (tid == 0)
            lpD[((size_t)g * Q + q) * 256 + blockIdx.x] =
                (((lredD[0] + lredD[1]) + (lredD[2] + lredD[3])) +
                 ((lredD[4] + lredD[5]) + (lredD[6] + lredD[7])));
        __syncthreads();
    }
}

// ---------------- K4: output projection out = (h - res) @ Wout_g^T + bout ----------------
__global__ __launch_bounds__(256) void k_proj_out(const float* __restrict__ ws,
                                                  const float* __restrict__ Wout,
                                                  const float* __restrict__ bout,
                                                  float* __restrict__ out) {
    __shared__ float As[32][65];
    __shared__ float Bs[32][65];
    const int g  = blockIdx.z;
    const int t0 = blockIdx.x * 64;
    const int d0 = blockIdx.y * 64;
    const int tid = threadIdx.x;
    const int tx = tid & 15, ty = tid >> 4;
    float acc[4][4] = {};
    const float* Ah = ws + WS_H + ((size_t)g * T + t0) * CD;
    const float* Ar = ws + WS_RES + ((size_t)g * T + t0) * CD;
    const float* Bb = Wout + (size_t)g * DG * CD + (size_t)d0 * CD;

    for (int k0 = 0; k0 < CD; k0 += 32) {
        __syncthreads();
#pragma unroll
        for (int j = 0; j < 8; j++) {
            int lin = j * 256 + tid;
            int k = lin & 31, r = lin >> 5;
            size_t o = (size_t)r * CD + k0 + k;
            As[k][r] = Ah[o] - Ar[o];            // qout = h - res_final
            Bs[k][r] = Bb[o];
        }
        __syncthreads();
#pragma unroll
        for (int k = 0; k < 32; k++) {
            float a[4], b[4];
#pragma unroll
            for (int i = 0; i < 4; i++) a[i] = As[k][ty + 16 * i];
#pragma unroll
            for (int j = 0; j < 4; j++) b[j] = Bs[k][tx + 16 * j];
#pragma unroll
            for (int i = 0; i < 4; i++)
#pragma unroll
                for (int j = 0; j < 4; j++) acc[i][j] = fmaf(a[i], b[j], acc[i][j]);
        }
    }
#pragma unroll
    for (int i = 0; i < 4; i++) {
        int t = t0 + ty + 16 * i;
#pragma unroll
        for (int j = 0; j < 4; j++) {
            int d = d0 + tx + 16 * j;
            out[(size_t)t * DIMV + (size_t)g * DG + d] = acc[i][j] + bout[g * DG + d];
        }
    }
}

// ---------------- K5: deterministic loss reduction (f64 -> f32) ----------------
__global__ void k_loss(const float* __restrict__ ws, float* __restrict__ out) {
    int gq = blockIdx.x;
    const double* lpD = (const double*)(ws + WS_LPARTD);
    double v = lpD[(size_t)gq * 256 + threadIdx.x];
#pragma unroll
    for (int m = 1; m < 64; m <<= 1) v += __shfl_xor(v, m, 64);
    __shared__ double red[4];
    if ((threadIdx.x & 63) == 0) red[threadIdx.x >> 6] = v;
    __syncthreads();
    if (threadIdx.x == 0)
        out[OUT_LOSS + gq] =
            (float)(((red[0] + red[1]) + (red[2] + red[3])) * (1.0 / 8388608.0));
}

extern "C" void kernel_launch(void* const* d_in, const int* in_sizes, int n_in,
                              void* d_out, int out_size, void* d_ws, size_t ws_size,
                              hipStream_t stream) {
    const float* x    = (const float*)d_in[0];
    const float* Win  = (const float*)d_in[1];
    const float* bin  = (const float*)d_in[2];
    const float* Wout = (const float*)d_in[3];
    const float* bout = (const float*)d_in[4];
    const float* cb   = (const float*)d_in[5];
    float* out = (float*)d_out;
    float* ws  = (float*)d_ws;

    // bf16 hi/lo codebook scratch in the not-yet-written quantized region of
    // d_out: 2*G*Q*K*CD bf16 = 4.2M f32-equiv << 41.9M f32 region.
    short* scr = (short*)d_out;
    short* cbh = scr;
    short* cbl = scr + (size_t)G * Q * KCODES * CD;

    hipLaunchKernelGGL(k_norms,    dim3(64),          dim3(256), 0, stream, cb, ws);
    hipLaunchKernelGGL(k_split,    dim3(4096),        dim3(256), 0, stream, cb, cbh, cbl);
    hipLaunchKernelGGL(k_proj_in,  dim3(T/64, 4, G),  dim3(256), 0, stream, x, Win, bin, ws);
    hipLaunchKernelGGL(k_rvq,      dim3(T/TM, G),     dim3(512), 0, stream, cb, ws, out, cbh, cbl);
    hipLaunchKernelGGL(k_proj_out, dim3(T/64, 10, G), dim3(256), 0, stream, ws, Wout, bout, out);
    hipLaunchKernelGGL(k_loss,     dim3(16),          dim3(256), 0, stream, ws, out);
}

// Round 16
// 1946.661 us; speedup vs baseline: 1.4707x; 1.0822x over previous
//
#include <hip/hip_runtime.h>
#include <hip/hip_bf16.h>

// Grouped Residual VQ: G=2, Q=8, K=1024, CD=256, DIM=1280 (DG=640), T=32768.
//
// Round 16 = r15 + PRE-TRANSPOSED codebook scratch:
// k_split now writes the bf16 hi/lo codebook in the exact LDS unit order the
// MFMA loop reads ([chunk][plane][dc][ku][code64]) -> k_rvq staging is a pure
// linear copy (1 KB contiguous per gl_lds instruction, fully coalesced) AND
// the ds_read pattern is r14's measured-zero-conflict layout. This combines
// r14's 0-conflict reads with r15's coalesced staging.

#define G 2
#define Q 8
#define KCODES 1024
#define CD 256
#define DIMV 1280
#define DG 640
#define T 32768
#define TM 128

#define WS_H      ((size_t)0)
#define WS_RES    (WS_H + (size_t)G*T*CD)
#define WS_CNORM  (WS_RES + (size_t)G*T*CD)
#define WS_CN64   (WS_CNORM + (size_t)G*Q*KCODES)
#define WS_LPARTD (WS_CN64 + (size_t)2*G*Q*KCODES)

#define OUT_IDX   ((size_t)T*DIMV)
#define OUT_LOSS  (OUT_IDX + (size_t)G*T*Q)

#define EPS_REFINE 2e-3f
#define ERRB 1e-3

typedef __attribute__((ext_vector_type(8))) short s16x8;
typedef __attribute__((ext_vector_type(4))) float f32x4;

static __device__ __forceinline__ unsigned short f2bf(float v) {
    __hip_bfloat16 b = __float2bfloat16(v);
    return *(unsigned short*)&b;
}
static __device__ __forceinline__ float bf2f(unsigned short u) {
    __hip_bfloat16 b = *(__hip_bfloat16*)&u;
    return __bfloat162float(b);
}

static __device__ __forceinline__ void gl_lds16(const void* g, void* l) {
    __builtin_amdgcn_global_load_lds(
        (const __attribute__((address_space(1))) unsigned int*)g,
        (__attribute__((address_space(3))) unsigned int*)l, 16, 0, 0);
}

__device__ __forceinline__ float np_half_sumsq(const float4* __restrict__ p) {
    float4 a = p[0], b = p[1];
    float r0=a.x*a.x, r1=a.y*a.y, r2=a.z*a.z, r3=a.w*a.w;
    float r4=b.x*b.x, r5=b.y*b.y, r6=b.z*b.z, r7=b.w*b.w;
#pragma unroll
    for (int i = 1; i < 16; i++) {
        a = p[2*i]; b = p[2*i+1];
        r0 += a.x*a.x; r1 += a.y*a.y; r2 += a.z*a.z; r3 += a.w*a.w;
        r4 += b.x*b.x; r5 += b.y*b.y; r6 += b.z*b.z; r7 += b.w*b.w;
    }
    return ((r0+r1)+(r2+r3)) + ((r4+r5)+(r6+r7));
}

// ---------------- K1: codebook norms (f32 + exact f64) ----------------
__global__ void k_norms(const float* __restrict__ cb, float* __restrict__ ws) {
    int r = blockIdx.x * 256 + threadIdx.x;
    const float4* row = (const float4*)(cb + (size_t)r * CD);
    ws[WS_CNORM + r] = np_half_sumsq(row) + np_half_sumsq(row + 32);
    double s0=0, s1=0, s2=0, s3=0;
#pragma unroll 8
    for (int e = 0; e < 64; e++) {
        float4 v = row[e];
        s0 = fma((double)v.x,(double)v.x,s0); s1 = fma((double)v.y,(double)v.y,s1);
        s2 = fma((double)v.z,(double)v.z,s2); s3 = fma((double)v.w,(double)v.w,s3);
    }
    ((double*)(ws + WS_CN64))[r] = (s0+s1)+(s2+s3);
}

// ---------------- K1b: codebook bf16 hi/lo split + LDS-order transpose ----------------
// cbt unit order: [(gq*16+cc)*2+pl][dc 8][ku 4][code64 64] (16B units).
__global__ void k_split(const float* __restrict__ cb, short* __restrict__ cbt) {
    int tau = blockIdx.x * 256 + threadIdx.x;     // 0 .. G*Q*KCODES*32-1
    int u = tau & 31;                             // dim unit within row
    int row = tau >> 5;                           // global code row 0..G*Q*K-1
    int gq = row >> 10;
    int code = row & 1023;
    int cc = code >> 6, c64 = code & 63;
    const float* src = cb + (size_t)row * CD + u * 8;
    float4 v0 = *(const float4*)src;
    float4 v1 = *(const float4*)(src + 4);
    float v[8] = {v0.x,v0.y,v0.z,v0.w,v1.x,v1.y,v1.z,v1.w};
    s16x8 hh, ll;
#pragma unroll
    for (int e = 0; e < 8; e++) {
        unsigned short hb = f2bf(v[e]);
        hh[e] = (short)hb;
        ll[e] = (short)f2bf(v[e] - bf2f(hb));
    }
    int n = (u >> 2) * 256 + (u & 3) * 64 + c64;  // dc*256 + ku*64 + code64
    size_t base = ((size_t)(gq * 16 + cc) * 2) * 2048;
    *(s16x8*)(cbt + (base + n) * 8)        = hh;  // plane 0 (hi)
    *(s16x8*)(cbt + (base + 2048 + n) * 8) = ll;  // plane 1 (lo)
}

// ---------------- K2: input projection h = x_g @ Win_g^T + bin ----------------
__global__ __launch_bounds__(256) void k_proj_in(const float* __restrict__ x,
                                                 const float* __restrict__ Win,
                                                 const float* __restrict__ bin,
                                                 float* __restrict__ ws) {
    __shared__ float As[32][65];
    __shared__ float Bs[32][65];
    const int g  = blockIdx.z;
    const int t0 = blockIdx.x * 64;
    const int c0 = blockIdx.y * 64;
    const int tid = threadIdx.x;
    const int tx = tid & 15, ty = tid >> 4;
    float acc[4][4] = {};
    const float* Ab = x + (size_t)t0 * DIMV + (size_t)g * DG;
    const float* Bb = Win + (size_t)g * CD * DG + (size_t)c0 * DG;

    for (int k0 = 0; k0 < DG; k0 += 32) {
        __syncthreads();
#pragma unroll
        for (int j = 0; j < 8; j++) {
            int lin = j * 256 + tid;
            int k = lin & 31, r = lin >> 5;
            As[k][r] = Ab[(size_t)r * DIMV + k0 + k];
            Bs[k][r] = Bb[(size_t)r * DG + k0 + k];
        }
        __syncthreads();
#pragma unroll
        for (int k = 0; k < 32; k++) {
            float a[4], b[4];
#pragma unroll
            for (int i = 0; i < 4; i++) a[i] = As[k][ty + 16 * i];
#pragma unroll
            for (int j = 0; j < 4; j++) b[j] = Bs[k][tx + 16 * j];
#pragma unroll
            for (int i = 0; i < 4; i++)
#pragma unroll
                for (int j = 0; j < 4; j++) acc[i][j] = fmaf(a[i], b[j], acc[i][j]);
        }
    }
#pragma unroll
    for (int i = 0; i < 4; i++) {
        int t = t0 + ty + 16 * i;
        float* hrow = ws + WS_H + ((size_t)g * T + t) * CD;
#pragma unroll
        for (int j = 0; j < 4; j++) {
            int c = c0 + tx + 16 * j;
            hrow[c] = acc[i][j] + bin[g * CD + c];
        }
    }
}

// ---------------- K3: fused ResidualVQ (reg-resident residual, linear staging) ----------------
#define STE1(rv, cv) { float tt_ = __fsub_rn((cv), (rv)); float qq_ = __fadd_rn((rv), tt_); \
                       float rr_ = __fsub_rn((rv), qq_); lacc += (double)rr_ * rr_; (rv) = rr_; }

__global__ __launch_bounds__(512, 2) void k_rvq(const float* __restrict__ cb,
                                                float* __restrict__ ws,
                                                float* __restrict__ out,
                                                const short* __restrict__ cbt) {
    __shared__ s16x8 CbV[2][4096];               // 128 KB: [pl 2][dc 8][ku 4][code64 64]
    __shared__ float cnS[KCODES];                // 4 KB
    __shared__ __align__(16) float refS[8][256]; // 8 KB per-wave refinement scratch
    __shared__ double lredD[8];

    const int g  = blockIdx.y;
    const int t0 = blockIdx.x * TM;
    const int tid = threadIdx.x;
    const int lane = tid & 63, l15 = lane & 15, l4 = lane >> 4;
    const int wv = tid >> 6;
    const size_t gT = (size_t)g * T;
    const int myTok = wv * 16 + l15;
    const float* cng = ws + WS_CNORM + (size_t)g * Q * KCODES;
    double* lpD = (double*)(ws + WS_LPARTD);

    // LINEAR staging geometry: load k fills LDS units [(wv*8+k)*64, +64) from
    // the identically-ordered global scratch -> fully coalesced 1KB per instr.
    size_t coff[8];
#pragma unroll
    for (int k = 0; k < 8; k++)
        coff[k] = (size_t)((wv * 8 + k) * 64 + lane) * 8;   // shorts

    // ---- residual (f32) lives in registers for the whole kernel ----
    float4 rA[8], rB[8];
    {
        const float* hrow = ws + WS_H + (gT + t0 + myTok) * CD + l4 * 8;
#pragma unroll
        for (int dc = 0; dc < 8; dc++) {
            rA[dc] = *(const float4*)(hrow + dc * 32);
            rB[dc] = *(const float4*)(hrow + dc * 32 + 4);
        }
    }

    for (int q = 0; q < Q; q++) {
        const float* cnq = cng + (size_t)q * KCODES;
        const double* cn64q = (const double*)(ws + WS_CN64) + ((size_t)g * Q + q) * KCODES;
        const float* cqb = cb + ((size_t)g * Q + q) * KCODES * CD;
        const short* cbtq = cbt + ((size_t)(g * Q + q) * 16 * 2 * 2048) * 8;

        cnS[tid] = cnq[tid];
        cnS[512 + tid] = cnq[512 + tid];

        // ---- split register residual to bf16 hi/lo fragments (pure VALU) ----
        s16x8 fh[8], fl[8];
#pragma unroll
        for (int dc = 0; dc < 8; dc++) {
            float v[8] = {rA[dc].x, rA[dc].y, rA[dc].z, rA[dc].w,
                          rB[dc].x, rB[dc].y, rB[dc].z, rB[dc].w};
            s16x8 th, tl;
#pragma unroll
            for (int e = 0; e < 8; e++) {
                unsigned short hb = f2bf(v[e]);
                th[e] = (short)hb;
                tl[e] = (short)f2bf(v[e] - bf2f(hb));
            }
            fh[dc] = th; fl[dc] = tl;
        }

        // stage chunk 0 into buf 0
#pragma unroll
        for (int k = 0; k < 8; k++)
            gl_lds16(cbtq + coff[k], &CbV[0][(wv * 8 + k) * 64]);
        __syncthreads();

        // top-3 values + top-2 indices (total order: value, then index)
        float tv1 = 3.4e38f, tv2 = 3.4e38f, tv3 = 3.4e38f;
        int   tix = 0x7fffffff, tix2 = 0x7fffffff;
        f32x4 acc[4];
#pragma unroll
        for (int t = 0; t < 4; t++) acc[t] = (f32x4){0.f, 0.f, 0.f, 0.f};

        for (int cc = 0; cc < 16; cc++) {
            __builtin_amdgcn_s_barrier();
            if (cc + 1 < 16) {
                const size_t add = (size_t)(cc + 1) * 32768;   // 2*2048 units * 8 shorts
#pragma unroll
                for (int k = 0; k < 8; k++)
                    gl_lds16(cbtq + add + coff[k], &CbV[(cc + 1) & 1][(wv * 8 + k) * 64]);
                asm volatile("s_waitcnt vmcnt(8)" ::: "memory");
            } else {
                asm volatile("s_waitcnt vmcnt(0)" ::: "memory");
            }
            __builtin_amdgcn_s_barrier();
            __builtin_amdgcn_sched_barrier(0);

            const int buf = cc & 1;
#pragma unroll
            for (int dc = 0; dc < 8; dc++) {
#pragma unroll
                for (int t = 0; t < 4; t++) {
                    int idx = dc * 256 + l4 * 64 + t * 16 + l15;   // r14 zero-conflict pattern
                    s16x8 ch = CbV[buf][idx];
                    s16x8 cl2 = CbV[buf][2048 + idx];
                    acc[t] = __builtin_amdgcn_mfma_f32_16x16x32_bf16(ch, fh[dc], acc[t], 0, 0, 0);
                    acc[t] = __builtin_amdgcn_mfma_f32_16x16x32_bf16(ch, fl[dc], acc[t], 0, 0, 0);
                    acc[t] = __builtin_amdgcn_mfma_f32_16x16x32_bf16(cl2, fh[dc], acc[t], 0, 0, 0);
                }
            }
            // score chunk cc (candidates arrive in ascending c within each lane)
#pragma unroll
            for (int t = 0; t < 4; t++)
#pragma unroll
                for (int r = 0; r < 4; r++) {
                    int c = cc * 64 + t * 16 + l4 * 4 + r;
                    float vv = fmaf(-2.f, acc[t][r], cnS[c]);
                    if (vv < tv1)      { tv3 = tv2; tv2 = tv1; tix2 = tix; tv1 = vv; tix = c; }
                    else if (vv < tv2) { tv3 = tv2; tv2 = vv; tix2 = c; }
                    else if (vv < tv3) { tv3 = vv; }
                }
#pragma unroll
            for (int t = 0; t < 4; t++) acc[t] = (f32x4){0.f, 0.f, 0.f, 0.f};
        }

        // ---- merge the 4 same-token lanes: sorted-triple merge (strides 16,32) ----
#pragma unroll
        for (int m = 16; m < 64; m <<= 1) {
            float b1 = __shfl_xor(tv1, m, 64);
            int   bi1 = __shfl_xor(tix, m, 64);
            float b2 = __shfl_xor(tv2, m, 64);
            int   bi2 = __shfl_xor(tix2, m, 64);
            float b3 = __shfl_xor(tv3, m, 64);
            float n1, n2, n3; int ni1, ni2;
            bool bf = (b1 < tv1) || (b1 == tv1 && bi1 < tix);
            if (bf) {
                n1 = b1; ni1 = bi1;
                bool af = (tv1 < b2) || (tv1 == b2 && tix < bi2);
                if (af) { n2 = tv1; ni2 = tix; n3 = fminf(tv2, b2); }
                else    { n2 = b2;  ni2 = bi2; n3 = fminf(tv1, b3); }
            } else {
                n1 = tv1; ni1 = tix;
                bool bs = (b1 < tv2) || (b1 == tv2 && bi1 < tix2);
                if (bs) { n2 = b1;  ni2 = bi1;  n3 = fminf(tv2, b2); }
                else    { n2 = tv2; ni2 = tix2; n3 = fminf(b1, tv3); }
            }
            tv1 = n1; tix = ni1; tv2 = n2; tix2 = ni2; tv3 = n3;
        }

        // ---- cheap exact refinement: f64 scores of top-2 only ----
        int besti = tix;
        bool flag = (tv2 - tv1 < EPS_REFINE);
        bool need_full = false;
        if (__any(flag)) {
            const float* c1r = cqb + (size_t)tix  * CD + l4 * 8;
            const float* c2r = cqb + (size_t)tix2 * CD + l4 * 8;
            double d1 = 0.0, d2 = 0.0;
#pragma unroll
            for (int dc = 0; dc < 8; dc++) {
                float4 p0 = *(const float4*)(c1r + dc * 32);
                float4 p1 = *(const float4*)(c1r + dc * 32 + 4);
                float4 q0 = *(const float4*)(c2r + dc * 32);
                float4 q1 = *(const float4*)(c2r + dc * 32 + 4);
                d1 = fma((double)rA[dc].x,(double)p0.x,d1); d1 = fma((double)rA[dc].y,(double)p0.y,d1);
                d1 = fma((double)rA[dc].z,(double)p0.z,d1); d1 = fma((double)rA[dc].w,(double)p0.w,d1);
                d1 = fma((double)rB[dc].x,(double)p1.x,d1); d1 = fma((double)rB[dc].y,(double)p1.y,d1);
                d1 = fma((double)rB[dc].z,(double)p1.z,d1); d1 = fma((double)rB[dc].w,(double)p1.w,d1);
                d2 = fma((double)rA[dc].x,(double)q0.x,d2); d2 = fma((double)rA[dc].y,(double)q0.y,d2);
                d2 = fma((double)rA[dc].z,(double)q0.z,d2); d2 = fma((double)rA[dc].w,(double)q0.w,d2);
                d2 = fma((double)rB[dc].x,(double)q1.x,d2); d2 = fma((double)rB[dc].y,(double)q1.y,d2);
                d2 = fma((double)rB[dc].z,(double)q1.z,d2); d2 = fma((double)rB[dc].w,(double)q1.w,d2);
            }
#pragma unroll
            for (int m = 16; m < 64; m <<= 1) {
                d1 += __shfl_xor(d1, m, 64);
                d2 += __shfl_xor(d2, m, 64);
            }
            double s1 = fma(-2.0, d1, cn64q[tix]);
            double s2 = fma(-2.0, d2, cn64q[tix2]);
            bool c2wins = (s2 < s1) || (s2 == s1 && tix2 < tix);
            double swin = c2wins ? s2 : s1;
            int    iwin = c2wins ? tix2 : tix;
            if (flag) besti = iwin;
            need_full = flag && !(swin < (double)tv3 - ERRB);
        }

        // ---- rare fallback: serial full f64 scan ----
        unsigned long long flg = __ballot(need_full) & 0xFFFFull;
        while (flg) {
            int l = __builtin_ctzll(flg); flg &= flg - 1;
            if (l15 == l) {
#pragma unroll
                for (int dc = 0; dc < 8; dc++) {
                    *(float4*)(&refS[wv][dc * 32 + l4 * 8])     = rA[dc];
                    *(float4*)(&refS[wv][dc * 32 + l4 * 8 + 4]) = rB[dc];
                }
            }
            asm volatile("s_waitcnt lgkmcnt(0)" ::: "memory");
            __builtin_amdgcn_sched_barrier(0);
            const float4* rf4 = (const float4*)(&refS[wv][0]);
            double bv = 1e300; int bi = 0x7fffffff;
            for (int c = lane; c < KCODES; c += 64) {
                const float4* cp4 = (const float4*)(cqb + (size_t)c * CD);
                double a0=0, a1=0, a2=0, a3=0;
#pragma unroll 4
                for (int e = 0; e < 64; e++) {
                    float4 cv = cp4[e], rv = rf4[e];
                    a0 = fma((double)rv.x,(double)cv.x,a0); a1 = fma((double)rv.y,(double)cv.y,a1);
                    a2 = fma((double)rv.z,(double)cv.z,a2); a3 = fma((double)rv.w,(double)cv.w,a3);
                }
                double dd = fma(-2.0, (a0+a1)+(a2+a3), cn64q[c]);
                if (dd < bv) { bv = dd; bi = c; }
            }
#pragma unroll
            for (int m = 1; m < 64; m <<= 1) {
                double ov = __shfl_xor(bv, m, 64);
                int    oi = __shfl_xor(bi, m, 64);
                if (ov < bv || (ov == bv && oi < bi)) { bv = ov; bi = oi; }
            }
            if (l15 == l) besti = bi;
            asm volatile("s_waitcnt lgkmcnt(0)" ::: "memory");
        }

        // ---- idx out (lane<16 holds token wv*16+lane) ----
        if (lane < 16)
            out[OUT_IDX + (gT + t0 + wv * 16 + lane) * Q + q] = (float)besti;

        // ---- STE update in registers from gathered code row ----
        double lacc = 0.0;
        {
            const float* crow = cqb + (size_t)besti * CD + l4 * 8;
#pragma unroll
            for (int dc = 0; dc < 8; dc++) {
                float4 c0 = *(const float4*)(crow + dc * 32);
                float4 c1 = *(const float4*)(crow + dc * 32 + 4);
                STE1(rA[dc].x, c0.x); STE1(rA[dc].y, c0.y);
                STE1(rA[dc].z, c0.z); STE1(rA[dc].w, c0.w);
                STE1(rB[dc].x, c1.x); STE1(rB[dc].y, c1.y);
                STE1(rB[dc].z, c1.z); STE1(rB[dc].w, c1.w);
            }
        }
        if (q == Q - 1) {
            float* rrow = ws + WS_RES + (gT + t0 + myTok) * CD + l4 * 8;
#pragma unroll
            for (int dc = 0; dc < 8; dc++) {
                *(float4*)(rrow + dc * 32)     = rA[dc];
                *(float4*)(rrow + dc * 32 + 4) = rB[dc];
            }
        }

        // ---- deterministic loss partial (f64) ----
#pragma unroll
        for (int m = 1; m < 64; m <<= 1) lacc += __shfl_xor(lacc, m, 64);
        __syncthreads();
        if (lane == 0) lredD[wv] = lacc;
        __syncthreads();
        if (tid == 0)
            lpD[((size_t)g * Q + q) * 256 + blockIdx.x] =
                (((lredD[0] + lredD[1]) + (lredD[2] + lredD[3])) +
                 ((lredD[4] + lredD[5]) + (lredD[6] + lredD[7])));
        __syncthreads();
    }
}

// ---------------- K4: output projection out = (h - res) @ Wout_g^T + bout ----------------
__global__ __launch_bounds__(256) void k_proj_out(const float* __restrict__ ws,
                                                  const float* __restrict__ Wout,
                                                  const float* __restrict__ bout,
                                                  float* __restrict__ out) {
    __shared__ float As[32][65];
    __shared__ float Bs[32][65];
    const int g  = blockIdx.z;
    const int t0 = blockIdx.x * 64;
    const int d0 = blockIdx.y * 64;
    const int tid = threadIdx.x;
    const int tx = tid & 15, ty = tid >> 4;
    float acc[4][4] = {};
    const float* Ah = ws + WS_H + ((size_t)g * T + t0) * CD;
    const float* Ar = ws + WS_RES + ((size_t)g * T + t0) * CD;
    const float* Bb = Wout + (size_t)g * DG * CD + (size_t)d0 * CD;

    for (int k0 = 0; k0 < CD; k0 += 32) {
        __syncthreads();
#pragma unroll
        for (int j = 0; j < 8; j++) {
            int lin = j * 256 + tid;
            int k = lin & 31, r = lin >> 5;
            size_t o = (size_t)r * CD + k0 + k;
            As[k][r] = Ah[o] - Ar[o];            // qout = h - res_final
            Bs[k][r] = Bb[o];
        }
        __syncthreads();
#pragma unroll
        for (int k = 0; k < 32; k++) {
            float a[4], b[4];
#pragma unroll
            for (int i = 0; i < 4; i++) a[i] = As[k][ty + 16 * i];
#pragma unroll
            for (int j = 0; j < 4; j++) b[j] = Bs[k][tx + 16 * j];
#pragma unroll
            for (int i = 0; i < 4; i++)
#pragma unroll
                for (int j = 0; j < 4; j++) acc[i][j] = fmaf(a[i], b[j], acc[i][j]);
        }
    }
#pragma unroll
    for (int i = 0; i < 4; i++) {
        int t = t0 + ty + 16 * i;
#pragma unroll
        for (int j = 0; j < 4; j++) {
            int d = d0 + tx + 16 * j;
            out[(size_t)t * DIMV + (size_t)g * DG + d] = acc[i][j] + bout[g * DG + d];
        }
    }
}

// ---------------- K5: deterministic loss reduction (f64 -> f32) ----------------
__global__ void k_loss(const float* __restrict__ ws, float* __restrict__ out) {
    int gq = blockIdx.x;
    const double* lpD = (const double*)(ws + WS_LPARTD);
    double v = lpD[(size_t)gq * 256 + threadIdx.x];
#pragma unroll
    for (int m = 1; m < 64; m <<= 1) v += __shfl_xor(v, m, 64);
    __shared__ double red[4];
    if ((threadIdx.x & 63) == 0) red[threadIdx.x >> 6] = v;
    __syncthreads();
    if (threadIdx.x == 0)
        out[OUT_LOSS + gq] =
            (float)(((red[0] + red[1]) + (red[2] + red[3])) * (1.0 / 8388608.0));
}

extern "C" void kernel_launch(void* const* d_in, const int* in_sizes, int n_in,
                              void* d_out, int out_size, void* d_ws, size_t ws_size,
                              hipStream_t stream) {
    const float* x    = (const float*)d_in[0];
    const float* Win  = (const float*)d_in[1];
    const float* bin  = (const float*)d_in[2];
    const float* Wout = (const float*)d_in[3];
    const float* bout = (const float*)d_in[4];
    const float* cb   = (const float*)d_in[5];
    float* out = (float*)d_out;
    float* ws  = (float*)d_ws;

    // Pre-transposed bf16 hi/lo codebook in the not-yet-written quantized
    // region of d_out: G*Q*K*CD*2 planes = 8.4M shorts = 4.2M f32-equiv
    // << 41.9M f32 region (k_proj_out overwrites the region at the end).
    short* cbt = (short*)d_out;

    hipLaunchKernelGGL(k_norms,    dim3(64),          dim3(256), 0, stream, cb, ws);
    hipLaunchKernelGGL(k_split,    dim3(2048),        dim3(256), 0, stream, cb, cbt);
    hipLaunchKernelGGL(k_proj_in,  dim3(T/64, 4, G),  dim3(256), 0, stream, x, Win, bin, ws);
    hipLaunchKernelGGL(k_rvq,      dim3(T/TM, G),     dim3(512), 0, stream, cb, ws, out, cbt);
    hipLaunchKernelGGL(k_proj_out, dim3(T/64, 10, G), dim3(256), 0, stream, ws, Wout, bout, out);
    hipLaunchKernelGGL(k_loss,     dim3(16),          dim3(256), 0, stream, ws, out);
}